// Round 6
// baseline (1160.509 us; speedup 1.0000x reference)
//
#include <hip/hip_runtime.h>
#include <hip/hip_bf16.h>

// Meta3D block: LN1 -> QKV -> MFMA-attn(+rel-pos bias) -> proj(+ls1 resid)
//               LN2 -> FC1+GELU -> FC2(+ls2 resid)
// B=1024 imgs, N=49 tok, C=448. GEMMs are y = x @ W.T (NT), bf16 MFMA 16x16x32.
// R8: structural cleanup. (a) x1 eliminated -- proj writes the residual stream
// straight into the output buffer oc; LN2 + fc2 read it there; fc2 updates it
// in place. Per-row workspace 7808->6016 B, so IC can reach 1024 (half the
// launches) if ws >= ~300MB. (b) build_bias merged into convert_w (one launch).
// GEMM = R7's 256x256/16-wave/ring-4 counted-vmcnt template (best measured:
// fc2 133us; delivery-cap analysis says schedule variants within the 2-phase
// family are exhausted -- 8-phase port is the next GEMM lever).

#define NTOK 49
#define CDIM 448
#define NHEAD 8
#define DHID 1024
#define HQKV 1536
#define FHID 1792
#define QK_SCALE 0.1767766952966369f
#define INV_SCALE 5.656854249492381f

typedef __attribute__((ext_vector_type(8))) short bf16x8;
typedef __attribute__((ext_vector_type(4))) float f32x4;
typedef unsigned int u32;

__device__ __forceinline__ short f2b(float f) {
    __hip_bfloat16 h = __float2bfloat16(f);
    return *reinterpret_cast<short*>(&h);
}

// async global->LDS, 16B per lane; LDS dest = wave-uniform base + lane*16
__device__ __forceinline__ void gll16(const short* g, short* l) {
    __builtin_amdgcn_global_load_lds(
        (const __attribute__((address_space(1))) u32*)g,
        (__attribute__((address_space(3))) u32*)l, 16, 0, 0);
}

// ---------------- setup: weight fp32->bf16 + rel-pos bias expansion ----------------
__global__ __launch_bounds__(256) void convert_w(
    const float* __restrict__ s0, const float* __restrict__ s1,
    const float* __restrict__ s2, const float* __restrict__ s3,
    short* __restrict__ d0, short* __restrict__ d1,
    short* __restrict__ d2, short* __restrict__ d3,
    const float* __restrict__ biases, const int* __restrict__ bidx,
    float* __restrict__ bfull)
{
    int i = blockIdx.x * 256 + threadIdx.x;
    if (i < 688128) d0[i] = f2b(s0[i]);        // qkv_w 1536x448
    if (i < 458752) d1[i] = f2b(s1[i]);        // proj_w 448x1024
    if (i < 802816) { d2[i] = f2b(s2[i]);      // fc1_w 1792x448
                      d3[i] = f2b(s3[i]); }    // fc2_w 448x1792
    if (i < NHEAD * NTOK * NTOK) {             // bias -> full [8,49,49]
        int h = i / (NTOK * NTOK), p = i % (NTOK * NTOK);
        bfull[i] = biases[h * NTOK + bidx[p]];
    }
}

// ---------------- LayerNorm: fp32 -> bf16, one wave per 448-row ----------------
__global__ __launch_bounds__(256) void ln_kernel(
    const float* __restrict__ x, short* __restrict__ out,
    const float* __restrict__ g, const float* __restrict__ b)
{
    int row = blockIdx.x * 4 + (threadIdx.x >> 6);
    int lane = threadIdx.x & 63;
    const float* xr = x + (size_t)row * CDIM;
    float v[7];
    float s = 0.f;
#pragma unroll
    for (int i = 0; i < 7; i++) { v[i] = xr[i * 64 + lane]; s += v[i]; }
#pragma unroll
    for (int o = 32; o > 0; o >>= 1) s += __shfl_xor(s, o, 64);
    float mean = s * (1.0f / 448.0f);
    float q = 0.f;
#pragma unroll
    for (int i = 0; i < 7; i++) { float d = v[i] - mean; q += d * d; }
#pragma unroll
    for (int o = 32; o > 0; o >>= 1) q += __shfl_xor(q, o, 64);
    float rstd = rsqrtf(q * (1.0f / 448.0f) + 1e-5f);
    short* orow = out + (size_t)row * CDIM;
#pragma unroll
    for (int i = 0; i < 7; i++) {
        int c = i * 64 + lane;
        orow[c] = f2b((v[i] - mean) * rstd * g[c] + b[c]);
    }
}

// ---------------- bf16 NT GEMM, 256x256 tile, BK=32, 4-buf ring distance 3 ----------------
// 16 waves (1024 thr), wave grid 4(m) x 4(n), 64x64 out per wave (acc 4x4 f32x4
// = 64 AGPR). Per K-step each wave stages exactly 2 panels (A panel w, B panel
// w; 16 rows x 32 k, DMA dest = base + lane*16) and reads its 4 A + 4 B frags
// (same conflict-free panel layout as R3-R7).
// Ring: buffers 0..3, prefetch distance 3. At iter t each wave's outstanding
// DMAs are tiles t,t+1,t+2 (6); vmcnt(4) completes tile t, leaves 4 in flight
// across the raw s_barrier; after the barrier stage tile t+3 into buf (t+3)&3.
// Wait-before-barrier => after barrier ALL waves' tile-t panels are resident.
// EPI 0: out_bf16 = acc + bias[col]
// EPI 1: out_bf16 = gelu_exact(acc + bias[col])
// EPI 2: out_f32  = resid[row,col] + (acc + bias[col]) * ls[col]
//        (resid may alias outF: each element is read then written once by the
//         same thread, so in-place residual update is safe)
template <int EPI>
__global__ __launch_bounds__(1024, 4) void gemm_bt(
    const short* __restrict__ A,     // [M,K] bf16 (rows clamped if M%256)
    const short* __restrict__ W,     // [N,K] bf16 (rows clamped if N%256)
    const float* __restrict__ bias,  // [N]
    const float* __restrict__ ls,    // [N]   (EPI 2)
    const float* resid,              // [M,N] (EPI 2; may alias outF)
    float* outF,                     // (EPI 2)
    short* __restrict__ outB,        // (EPI 0/1)
    int M, int N, int K)
{
    __shared__ short sA[4][8192];   // 4 x 16KB : 256 rows x 32 k
    __shared__ short sB[4][8192];
    const int tid = threadIdx.x;
    const int lane = tid & 63;
    const int w = tid >> 6;          // 0..15
    const int lr = lane & 15, lq = lane >> 4;

    // m204 bijective XCD swizzle: same-y (same A-panel) blocks contiguous per XCD
    const int gx = gridDim.x;
    const int nwg = gx * gridDim.y;
    const int lin = blockIdx.y * gx + blockIdx.x;
    const int q8 = nwg >> 3, r8 = nwg & 7;
    const int xcd = lin & 7, sub = lin >> 3;
    const int wg = (xcd < r8 ? xcd * (q8 + 1) : r8 * (q8 + 1) + (xcd - r8) * q8) + sub;
    const int m0 = (wg / gx) * 256;
    const int n0 = (wg % gx) * 256;

    // staging: wave w owns A panel w and B panel w (rows clamped)
    int rA = m0 + w * 16 + lr; rA = rA < M ? rA : M - 1;
    int rB = n0 + w * 16 + lr; rB = rB < N ? rB : N - 1;
    const u32 kb = (u32)(K + K);          // row stride in bytes
    u32 oA = (u32)rA * kb + (u32)(lq * 16);
    u32 oB = (u32)rB * kb + (u32)(lq * 16);
    const int dst = w * 512;              // panel offset in shorts

    const f32x4 fz = {0.f, 0.f, 0.f, 0.f};
    f32x4 acc[4][4];
#pragma unroll
    for (int i = 0; i < 4; i++)
#pragma unroll
        for (int j = 0; j < 4; j++) acc[i][j] = fz;

    const int rdA = (w & 3) * 4096 + lane * 16;   // byte offset inside A buffer
    const int rdB = (w >> 2) * 4096 + lane * 16;  // byte offset inside B buffer

    const int nt = K >> 5;   // 14 / 32 / 56
    // prologue: stage tiles 0,1,2 into bufs 0,1,2
#pragma unroll
    for (int p = 0; p < 3; p++) {
        gll16((const short*)((const char*)A + oA), &sA[p][dst]);
        gll16((const short*)((const char*)W + oB), &sB[p][dst]);
        oA += 64; oB += 64;
    }

    int bc = 0;   // compute buffer
    int bs = 3;   // stage buffer
    for (int t = 0; t < nt; t++) {
        const int rem = nt - 1 - t;
        if (rem >= 2)      asm volatile("s_waitcnt vmcnt(4)" ::: "memory");
        else if (rem == 1) asm volatile("s_waitcnt vmcnt(2)" ::: "memory");
        else               asm volatile("s_waitcnt vmcnt(0)" ::: "memory");
        __builtin_amdgcn_s_barrier();
        if (t + 3 < nt) {
            gll16((const short*)((const char*)A + oA), &sA[bs][dst]);
            gll16((const short*)((const char*)W + oB), &sB[bs][dst]);
            oA += 64; oB += 64;
            bs = (bs + 1) & 3;
        }
        const char* baseA = (const char*)sA[bc] + rdA;
        const char* baseB = (const char*)sB[bc] + rdB;
        bc = (bc + 1) & 3;
        bf16x8 af[4], bfb[4];
#pragma unroll
        for (int i = 0; i < 4; i++) af[i] = *(const bf16x8*)(baseA + i * 1024);
#pragma unroll
        for (int j = 0; j < 4; j++) bfb[j] = *(const bf16x8*)(baseB + j * 1024);
#pragma unroll
        for (int i = 0; i < 4; i++)
#pragma unroll
            for (int j = 0; j < 4; j++)
                acc[i][j] = __builtin_amdgcn_mfma_f32_16x16x32_bf16(
                    af[i], bfb[j], acc[i][j], 0, 0, 0);
    }

    const int wm = (w & 3) * 64, wn = (w >> 2) * 64;
    // C/D layout: col=lane&15, row=(lane>>4)*4+reg  [verified m89/m91]
#pragma unroll
    for (int i = 0; i < 4; i++)
#pragma unroll
        for (int j = 0; j < 4; j++)
#pragma unroll
            for (int r = 0; r < 4; r++) {
                int row = m0 + wm + i * 16 + lq * 4 + r;
                int col = n0 + wn + j * 16 + lr;
                if (row < M && col < N) {
                    float v = acc[i][j][r] + bias[col];
                    if (EPI == 0) {
                        outB[(size_t)row * N + col] = f2b(v);
                    } else if (EPI == 1) {
                        float gl = 0.5f * v * (1.0f + erff(v * 0.7071067811865475f));
                        outB[(size_t)row * N + col] = f2b(gl);
                    } else {
                        outF[(size_t)row * N + col] =
                            resid[(size_t)row * N + col] + v * ls[col];
                    }
                }
            }
}

// ---------------- MFMA attention: 1 wave per (image, head) ----------------
// No V LDS staging, no barrier. V fragments gathered directly from global
// (predicated tok<49 -> 0). LDS = sP only (9KB) -> occupancy VGPR-bound.
__global__ __launch_bounds__(64) void attn_mfma(
    const short* __restrict__ qkv,    // [R,1536]; per-head 192 = q32|k32|v128
    const float* __restrict__ bfull,  // [8,49,49] fp32
    short* __restrict__ attn_out)     // [R,1024]
{
    __shared__ short sP[64 * 72];     // P bf16, row stride 144B (16B aligned)
    const int head = blockIdx.x;
    const size_t base = (size_t)blockIdx.y * NTOK;
    const int lane = threadIdx.x;
    const int lr = lane & 15, lq = lane >> 4;

    // C-init = bias/SCALE; mask cols>=49 with -1e30 (survives MFMA add + *SCALE)
    f32x4 sc[4][4];
#pragma unroll
    for (int i = 0; i < 4; i++)
#pragma unroll
        for (int j = 0; j < 4; j++)
#pragma unroll
            for (int r = 0; r < 4; r++) {
                int row = i * 16 + lq * 4 + r, col = j * 16 + lr;
                float v;
                if (col >= NTOK)      v = -1e30f;
                else if (row < NTOK)  v = bfull[head * (NTOK * NTOK) + row * NTOK + col] * INV_SCALE;
                else                  v = 0.f;
                sc[i][j][r] = v;
            }

    // Q/K fragments straight from global (k-contiguous 16B; rows clamped)
    bf16x8 qf[4], kf[4];
#pragma unroll
    for (int i = 0; i < 4; i++) {
        int r = i * 16 + lr; r = r < NTOK ? r : NTOK - 1;
        const short* rp = qkv + (base + r) * HQKV + head * 192;
        qf[i] = *(const bf16x8*)(rp + lq * 8);
        kf[i] = *(const bf16x8*)(rp + 32 + lq * 8);
    }
#pragma unroll
    for (int i = 0; i < 4; i++)
#pragma unroll
        for (int j = 0; j < 4; j++)
            sc[i][j] = __builtin_amdgcn_mfma_f32_16x16x32_bf16(
                qf[i], kf[j], sc[i][j], 0, 0, 0);

    // softmax over (j regs x 16 lanes) per output row; P -> sP as bf16
#pragma unroll
    for (int i = 0; i < 4; i++)
#pragma unroll
        for (int r = 0; r < 4; r++) {
            float s0 = sc[i][0][r] * QK_SCALE;
            float s1 = sc[i][1][r] * QK_SCALE;
            float s2 = sc[i][2][r] * QK_SCALE;
            float s3 = sc[i][3][r] * QK_SCALE;
            float m = fmaxf(fmaxf(s0, s1), fmaxf(s2, s3));
#pragma unroll
            for (int o = 1; o < 16; o <<= 1) m = fmaxf(m, __shfl_xor(m, o, 64));
            float e0 = __expf(s0 - m), e1 = __expf(s1 - m);
            float e2 = __expf(s2 - m), e3 = __expf(s3 - m);
            float l = e0 + e1 + e2 + e3;
#pragma unroll
            for (int o = 1; o < 16; o <<= 1) l += __shfl_xor(l, o, 64);
            float inv = 1.0f / l;
            short* pr = &sP[(i * 16 + lq * 4 + r) * 72];
            pr[lr]      = f2b(e0 * inv);
            pr[16 + lr] = f2b(e1 * inv);
            pr[32 + lr] = f2b(e2 * inv);
            pr[48 + lr] = f2b(e3 * inv);
        }
    // single wave: ds_write->ds_read ordered by lgkmcnt, no barrier needed

    // PV: A = P (rows=query, k=token), B rows = V^T[d][tok] gathered from
    // global: element e of frag (j,kk) is V[tok=kk*32+lq*8+e][d] (0 if tok>=49)
    bf16x8 pa[4][2];
#pragma unroll
    for (int i = 0; i < 4; i++)
#pragma unroll
        for (int kk = 0; kk < 2; kk++)
            pa[i][kk] = *(const bf16x8*)&sP[(i * 16 + lr) * 72 + kk * 32 + lq * 8];

#pragma unroll
    for (int half = 0; half < 2; half++) {
        const f32x4 fz = {0.f, 0.f, 0.f, 0.f};
        f32x4 o[4][4];
        bf16x8 pb[4][2];
#pragma unroll
        for (int j = 0; j < 4; j++)
#pragma unroll
            for (int kk = 0; kk < 2; kk++) {
                const int d = half * 64 + j * 16 + lr;
                const short* vcol = qkv + head * 192 + 64 + d;
                bf16x8 tvec;
#pragma unroll
                for (int e = 0; e < 8; e++) {
                    int tok = kk * 32 + lq * 8 + e;
                    tvec[e] = tok < NTOK ? vcol[(base + tok) * HQKV] : (short)0;
                }
                pb[j][kk] = tvec;
            }
#pragma unroll
        for (int i = 0; i < 4; i++)
#pragma unroll
            for (int j = 0; j < 4; j++) {
                o[i][j] = __builtin_amdgcn_mfma_f32_16x16x32_bf16(
                    pa[i][0], pb[j][0], fz, 0, 0, 0);
                o[i][j] = __builtin_amdgcn_mfma_f32_16x16x32_bf16(
                    pa[i][1], pb[j][1], o[i][j], 0, 0, 0);
            }
#pragma unroll
        for (int i = 0; i < 4; i++)
#pragma unroll
            for (int j = 0; j < 4; j++)
#pragma unroll
                for (int r = 0; r < 4; r++) {
                    int row = i * 16 + lq * 4 + r;
                    if (row < NTOK)
                        attn_out[(base + row) * DHID + head * 128 + half * 64 + j * 16 + lr] =
                            f2b(o[i][j][r]);
                }
    }
}

extern "C" void kernel_launch(void* const* d_in, const int* in_sizes, int n_in,
                              void* d_out, int out_size, void* d_ws, size_t ws_size,
                              hipStream_t stream) {
    const float* x      = (const float*)d_in[0];
    const float* qkv_w  = (const float*)d_in[1];
    const float* qkv_b  = (const float*)d_in[2];
    const float* proj_w = (const float*)d_in[3];
    const float* proj_b = (const float*)d_in[4];
    const float* fc1_w  = (const float*)d_in[5];
    const float* fc1_b  = (const float*)d_in[6];
    const float* fc2_w  = (const float*)d_in[7];
    const float* fc2_b  = (const float*)d_in[8];
    const float* n1g    = (const float*)d_in[9];
    const float* n1b    = (const float*)d_in[10];
    const float* n2g    = (const float*)d_in[11];
    const float* n2b    = (const float*)d_in[12];
    const float* ls1    = (const float*)d_in[13];
    const float* ls2    = (const float*)d_in[14];
    const float* biases = (const float*)d_in[15];
    const int*   bidx   = (const int*)d_in[16];
    float* outp = (float*)d_out;

    char* ws = (char*)d_ws;
    short* Wq = (short*)ws; ws += (size_t)688128 * 2;
    short* Wp = (short*)ws; ws += (size_t)458752 * 2;
    short* W1 = (short*)ws; ws += (size_t)802816 * 2;
    short* W2 = (short*)ws; ws += (size_t)802816 * 2;
    float* bfull = (float*)ws; ws += (size_t)NHEAD * NTOK * NTOK * 4;
    const size_t fixed = 5505024 + (size_t)NHEAD * NTOK * NTOK * 4;

    // per-row intermediates: hbuf 896B + qkvb 3072B + attb 2048B = 6016B
    // (x1 eliminated: residual stream lives in the output buffer)
    int IC = 1024;
    while (IC > 128) {
        size_t Rr = (size_t)IC * NTOK;
        if (fixed + Rr * 6016ull <= ws_size) break;
        IC >>= 1;
    }
    const size_t R = (size_t)IC * NTOK;
    short* hbuf = (short*)ws; ws += R * CDIM * 2;   // LN out (reused LN2)
    short* qkvb = (short*)ws; ws += R * HQKV * 2;
    short* attb = (short*)ws; ws += R * DHID * 2;
    short* gbuf = qkvb;  // FC1 out [R,1792] overlays qkvb+attb (dead by then)

    convert_w<<<3136, 256, 0, stream>>>(qkv_w, proj_w, fc1_w, fc2_w,
                                        Wq, Wp, W1, W2, biases, bidx, bfull);

    for (int c0 = 0; c0 < 1024; c0 += IC) {
        const float* xc = x + (size_t)c0 * NTOK * CDIM;
        float* oc = outp + (size_t)c0 * NTOK * CDIM;
        const int Ri = IC * NTOK;
        const int gy = (Ri + 255) / 256;

        ln_kernel<<<Ri / 4, 256, 0, stream>>>(xc, hbuf, n1g, n1b);
        gemm_bt<0><<<dim3(HQKV / 256, gy), 1024, 0, stream>>>(
            hbuf, Wq, qkv_b, nullptr, nullptr, nullptr, qkvb, Ri, HQKV, CDIM);
        attn_mfma<<<dim3(NHEAD, IC), 64, 0, stream>>>(qkvb, bfull, attb);
        // proj writes residual stream x + attn*ls1 straight into oc
        gemm_bt<2><<<dim3(2, gy), 1024, 0, stream>>>(
            attb, Wp, proj_b, ls1, xc, oc, nullptr, Ri, CDIM, DHID);
        ln_kernel<<<Ri / 4, 256, 0, stream>>>(oc, hbuf, n2g, n2b);
        gemm_bt<1><<<dim3(FHID / 256, gy), 1024, 0, stream>>>(
            hbuf, W1, fc1_b, nullptr, nullptr, nullptr, gbuf, Ri, FHID, CDIM);
        // fc2 in-place residual update: oc = oc + fc2(gbuf)*ls2
        gemm_bt<2><<<dim3(2, gy), 1024, 0, stream>>>(
            gbuf, W2, fc2_b, ls2, oc, oc, nullptr, Ri, CDIM, FHID);
    }
}

// Round 8
// 1019.253 us; speedup vs baseline: 1.1386x; 1.1386x over previous
//
#include <hip/hip_runtime.h>
#include <hip/hip_bf16.h>
#include <hip/hip_fp8.h>

// Meta3D block: LN1 -> QKV -> MFMA-attn(+rel-pos bias) -> proj(+ls1 resid)
//               LN2 -> FC1+GELU -> FC2(+ls2 resid)
// B=1024 imgs, N=49 tok, C=448. GEMMs y = x @ W.T (NT).
// R9 (resubmit; prev round was GPUAcquisitionTimeout, no data): fp8 staging.
// GEMM time follows staged volume / ~2.4TB/s delivery across R3-R8; tiles are
// maxed at 256^2, so halve BYTES: weights + GEMM activations (hbuf/attb/gbuf)
// in OCP e4m3, inner loop = mfma_f32_16x16x32_fp8_fp8. Branch errors are
// ls=1e-5-suppressed in the output -> fp8 safe.
// attn kernel stays bf16 (qkvb bf16) except its output store (attb fp8).
// Ring: 6 buffers, distance 5, counted vmcnt (R5-R8 invariant), 96KB LDS.

#define NTOK 49
#define CDIM 448
#define NHEAD 8
#define DHID 1024
#define HQKV 1536
#define FHID 1792
#define QK_SCALE 0.1767766952966369f
#define INV_SCALE 5.656854249492381f

typedef __attribute__((ext_vector_type(8))) short bf16x8;
typedef __attribute__((ext_vector_type(4))) float f32x4;
typedef unsigned int u32;
typedef unsigned char u8;

__device__ __forceinline__ short f2b(float f) {
    __hip_bfloat16 h = __float2bfloat16(f);
    return *reinterpret_cast<short*>(&h);
}
__device__ __forceinline__ u8 f2f8(float f) {
    __hip_fp8_e4m3 h(f);                 // OCP e4m3fn, saturating RNE
    return *reinterpret_cast<u8*>(&h);
}

// async global->LDS, 16B per lane; LDS dest = wave-uniform base + lane*16
__device__ __forceinline__ void gll16(const void* g, void* l) {
    __builtin_amdgcn_global_load_lds(
        (const __attribute__((address_space(1))) u32*)g,
        (__attribute__((address_space(3))) u32*)l, 16, 0, 0);
}

// ---------------- setup: weights fp32->fp8 + rel-pos bias expansion ----------------
__global__ __launch_bounds__(256) void convert_w(
    const float* __restrict__ s0, const float* __restrict__ s1,
    const float* __restrict__ s2, const float* __restrict__ s3,
    u8* __restrict__ d0, u8* __restrict__ d1,
    u8* __restrict__ d2, u8* __restrict__ d3,
    const float* __restrict__ biases, const int* __restrict__ bidx,
    float* __restrict__ bfull)
{
    int i = blockIdx.x * 256 + threadIdx.x;
    if (i < 688128) d0[i] = f2f8(s0[i]);       // qkv_w 1536x448
    if (i < 458752) d1[i] = f2f8(s1[i]);       // proj_w 448x1024
    if (i < 802816) { d2[i] = f2f8(s2[i]);     // fc1_w 1792x448
                      d3[i] = f2f8(s3[i]); }   // fc2_w 448x1792
    if (i < NHEAD * NTOK * NTOK) {             // bias -> full [8,49,49]
        int h = i / (NTOK * NTOK), p = i % (NTOK * NTOK);
        bfull[i] = biases[h * NTOK + bidx[p]];
    }
}

// ---------------- LayerNorm: fp32 -> fp8, one wave per 448-row ----------------
__global__ __launch_bounds__(256) void ln_kernel(
    const float* __restrict__ x, u8* __restrict__ out,
    const float* __restrict__ g, const float* __restrict__ b)
{
    int row = blockIdx.x * 4 + (threadIdx.x >> 6);
    int lane = threadIdx.x & 63;
    const float* xr = x + (size_t)row * CDIM;
    float v[7];
    float s = 0.f;
#pragma unroll
    for (int i = 0; i < 7; i++) { v[i] = xr[i * 64 + lane]; s += v[i]; }
#pragma unroll
    for (int o = 32; o > 0; o >>= 1) s += __shfl_xor(s, o, 64);
    float mean = s * (1.0f / 448.0f);
    float q = 0.f;
#pragma unroll
    for (int i = 0; i < 7; i++) { float d = v[i] - mean; q += d * d; }
#pragma unroll
    for (int o = 32; o > 0; o >>= 1) q += __shfl_xor(q, o, 64);
    float rstd = rsqrtf(q * (1.0f / 448.0f) + 1e-5f);
    u8* orow = out + (size_t)row * CDIM;
#pragma unroll
    for (int i = 0; i < 7; i++) {
        int c = i * 64 + lane;
        orow[c] = f2f8((v[i] - mean) * rstd * g[c] + b[c]);
    }
}

// ---------------- fp8 NT GEMM, 256x256 tile, BK=32, 6-buf ring distance 5 ----------------
// 16 waves, wave grid 4(m) x 4(n), 64x64 out per wave (acc 4x4 f32x4 = 64 AGPR).
// A-tile 256x32 fp8 = 8KB/buffer (ditto B). Staging: waves 0-7 stage A slab
// w*32 rows, waves 8-15 stage B slab (w-8)*32 rows; lane -> (row=lane>>1,
// half=lane&1), LDS dest linear lane*16 == row-major 32B rows. 1 gll/wave/step.
// Ring distance 5: at iter t outstanding tiles {t..t+4}; wait vmcnt(4) completes
// tile t, keeps 4 in flight across the raw s_barrier; stage tile t+5 after.
// Frag reads: 8B (long) per lane at (row_local)*32 + lq*8 (4-way bank alias,
// ~1.6x per m136 -- halved bytes still net win). MFMA 16x16x32 fp8: A/B frag =
// row=lr, k=lq*8+e (CDNA3-carried layout, mirrors verified bf16 mapping).
// EPI 0: out_bf16 = acc + bias[col]            (qkvb stays bf16 for attn)
// EPI 1: out_fp8  = gelu_exact(acc + bias[col])
// EPI 2: out_f32  = resid[row,col] + (acc + bias[col]) * ls[col]  (may alias)
template <int EPI>
__global__ __launch_bounds__(1024, 4) void gemm_bt(
    const u8* __restrict__ A,        // [M,K] fp8 (M % 256 == 0)
    const u8* __restrict__ W,        // [N,K] fp8 (rows clamped if N%256)
    const float* __restrict__ bias,  // [N]
    const float* __restrict__ ls,    // [N]   (EPI 2)
    const float* resid,              // [M,N] (EPI 2; may alias outF)
    float* outF,                     // (EPI 2)
    void* outX,                      // EPI 0: short*, EPI 1: u8*
    int M, int N, int K)
{
    __shared__ u8 sA[6][8192];
    __shared__ u8 sB[6][8192];
    const int tid = threadIdx.x;
    const int lane = tid & 63;
    const int w = tid >> 6;          // 0..15
    const int lr = lane & 15, lq = lane >> 4;

    // m204 bijective XCD swizzle
    const int gx = gridDim.x;
    const int nwg = gx * gridDim.y;
    const int lin = blockIdx.y * gx + blockIdx.x;
    const int q8 = nwg >> 3, r8 = nwg & 7;
    const int xcd = lin & 7, sub = lin >> 3;
    const int wg = (xcd < r8 ? xcd * (q8 + 1) : r8 * (q8 + 1) + (xcd - r8) * q8) + sub;
    const int m0 = (wg / gx) * 256;
    const int n0 = (wg % gx) * 256;

    // staging assignment: waves 0-7 -> A, 8-15 -> B; 32-row slab per wave
    const bool isB = (w >= 8);
    const int slab = w & 7;
    int srow = (isB ? n0 : m0) + slab * 32 + (lane >> 1);
    if (isB) srow = srow < N ? srow : N - 1;     // A rows never OOB (M%256==0)
    const u8* gsrc = isB ? W : A;
    u32 offs = (u32)srow * (u32)K + (u32)((lane & 1) * 16);
    const int dslab = slab * 1024;               // byte offset inside buffer

    const f32x4 fz = {0.f, 0.f, 0.f, 0.f};
    f32x4 acc[4][4];
#pragma unroll
    for (int i = 0; i < 4; i++)
#pragma unroll
        for (int j = 0; j < 4; j++) acc[i][j] = fz;

    const int rdA = (w & 3) * 2048 + lr * 32 + lq * 8;
    const int rdB = (w >> 2) * 2048 + lr * 32 + lq * 8;

    const int nt = K >> 5;   // 14 / 32 / 56 (all >= 6)
    // prologue: stage tiles 0..4
#pragma unroll
    for (int p = 0; p < 5; p++) {
        gll16(gsrc + offs, (isB ? sB[p] : sA[p]) + dslab);
        offs += 32;
    }

    int bc = 0;   // compute buffer
    int bs = 5;   // stage buffer
    for (int t = 0; t < nt; t++) {
        const int rem = nt - 1 - t;
        if (rem >= 4)      asm volatile("s_waitcnt vmcnt(4)" ::: "memory");
        else if (rem == 3) asm volatile("s_waitcnt vmcnt(3)" ::: "memory");
        else if (rem == 2) asm volatile("s_waitcnt vmcnt(2)" ::: "memory");
        else if (rem == 1) asm volatile("s_waitcnt vmcnt(1)" ::: "memory");
        else               asm volatile("s_waitcnt vmcnt(0)" ::: "memory");
        __builtin_amdgcn_s_barrier();
        if (t + 5 < nt) {
            gll16(gsrc + offs, (isB ? sB[bs] : sA[bs]) + dslab);
            offs += 32;
            bs = (bs == 5) ? 0 : bs + 1;
        }
        const u8* baseA = sA[bc] + rdA;
        const u8* baseB = sB[bc] + rdB;
        bc = (bc == 5) ? 0 : bc + 1;
        long af[4], bfr[4];
#pragma unroll
        for (int i = 0; i < 4; i++) af[i] = *(const long*)(baseA + i * 512);
#pragma unroll
        for (int j = 0; j < 4; j++) bfr[j] = *(const long*)(baseB + j * 512);
#pragma unroll
        for (int i = 0; i < 4; i++)
#pragma unroll
            for (int j = 0; j < 4; j++)
                acc[i][j] = __builtin_amdgcn_mfma_f32_16x16x32_fp8_fp8(
                    af[i], bfr[j], acc[i][j], 0, 0, 0);
    }

    const int wm = (w & 3) * 64, wn = (w >> 2) * 64;
    // C/D layout: col=lane&15, row=(lane>>4)*4+reg (shape-determined, m89/m101)
#pragma unroll
    for (int i = 0; i < 4; i++)
#pragma unroll
        for (int j = 0; j < 4; j++)
#pragma unroll
            for (int r = 0; r < 4; r++) {
                int row = m0 + wm + i * 16 + lq * 4 + r;
                int col = n0 + wn + j * 16 + lr;
                if (row < M && col < N) {
                    float v = acc[i][j][r] + bias[col];
                    if (EPI == 0) {
                        ((short*)outX)[(size_t)row * N + col] = f2b(v);
                    } else if (EPI == 1) {
                        float gl = 0.5f * v * (1.0f + erff(v * 0.7071067811865475f));
                        ((u8*)outX)[(size_t)row * N + col] = f2f8(gl);
                    } else {
                        outF[(size_t)row * N + col] =
                            resid[(size_t)row * N + col] + v * ls[col];
                    }
                }
            }
}

// ---------------- MFMA attention (bf16 internals): 1 wave per (image, head) ----------------
// qkv input bf16 (unchanged verified path); output store is fp8 (attb).
__global__ __launch_bounds__(64) void attn_mfma(
    const short* __restrict__ qkv,    // [R,1536] bf16; per-head 192 = q32|k32|v128
    const float* __restrict__ bfull,  // [8,49,49] fp32
    u8* __restrict__ attn_out)        // [R,1024] fp8
{
    __shared__ short sP[64 * 72];     // P bf16, row stride 144B (16B aligned)
    const int head = blockIdx.x;
    const size_t base = (size_t)blockIdx.y * NTOK;
    const int lane = threadIdx.x;
    const int lr = lane & 15, lq = lane >> 4;

    // C-init = bias/SCALE; mask cols>=49 with -1e30
    f32x4 sc[4][4];
#pragma unroll
    for (int i = 0; i < 4; i++)
#pragma unroll
        for (int j = 0; j < 4; j++)
#pragma unroll
            for (int r = 0; r < 4; r++) {
                int row = i * 16 + lq * 4 + r, col = j * 16 + lr;
                float v;
                if (col >= NTOK)      v = -1e30f;
                else if (row < NTOK)  v = bfull[head * (NTOK * NTOK) + row * NTOK + col] * INV_SCALE;
                else                  v = 0.f;
                sc[i][j][r] = v;
            }

    // Q/K fragments straight from global (k-contiguous 16B; rows clamped)
    bf16x8 qf[4], kf[4];
#pragma unroll
    for (int i = 0; i < 4; i++) {
        int r = i * 16 + lr; r = r < NTOK ? r : NTOK - 1;
        const short* rp = qkv + (base + r) * HQKV + head * 192;
        qf[i] = *(const bf16x8*)(rp + lq * 8);
        kf[i] = *(const bf16x8*)(rp + 32 + lq * 8);
    }
#pragma unroll
    for (int i = 0; i < 4; i++)
#pragma unroll
        for (int j = 0; j < 4; j++)
            sc[i][j] = __builtin_amdgcn_mfma_f32_16x16x32_bf16(
                qf[i], kf[j], sc[i][j], 0, 0, 0);

    // softmax over (j regs x 16 lanes) per output row; P -> sP as bf16
#pragma unroll
    for (int i = 0; i < 4; i++)
#pragma unroll
        for (int r = 0; r < 4; r++) {
            float s0 = sc[i][0][r] * QK_SCALE;
            float s1 = sc[i][1][r] * QK_SCALE;
            float s2 = sc[i][2][r] * QK_SCALE;
            float s3 = sc[i][3][r] * QK_SCALE;
            float m = fmaxf(fmaxf(s0, s1), fmaxf(s2, s3));
#pragma unroll
            for (int o = 1; o < 16; o <<= 1) m = fmaxf(m, __shfl_xor(m, o, 64));
            float e0 = __expf(s0 - m), e1 = __expf(s1 - m);
            float e2 = __expf(s2 - m), e3 = __expf(s3 - m);
            float l = e0 + e1 + e2 + e3;
#pragma unroll
            for (int o = 1; o < 16; o <<= 1) l += __shfl_xor(l, o, 64);
            float inv = 1.0f / l;
            short* pr = &sP[(i * 16 + lq * 4 + r) * 72];
            pr[lr]      = f2b(e0 * inv);
            pr[16 + lr] = f2b(e1 * inv);
            pr[32 + lr] = f2b(e2 * inv);
            pr[48 + lr] = f2b(e3 * inv);
        }
    // single wave: ds_write->ds_read ordered by lgkmcnt, no barrier needed

    // PV: A = P, B rows = V^T[d][tok] gathered from global (tok>=49 -> 0)
    bf16x8 pa[4][2];
#pragma unroll
    for (int i = 0; i < 4; i++)
#pragma unroll
        for (int kk = 0; kk < 2; kk++)
            pa[i][kk] = *(const bf16x8*)&sP[(i * 16 + lr) * 72 + kk * 32 + lq * 8];

#pragma unroll
    for (int half = 0; half < 2; half++) {
        const f32x4 fz = {0.f, 0.f, 0.f, 0.f};
        f32x4 o[4][4];
        bf16x8 pb[4][2];
#pragma unroll
        for (int j = 0; j < 4; j++)
#pragma unroll
            for (int kk = 0; kk < 2; kk++) {
                const int d = half * 64 + j * 16 + lr;
                const short* vcol = qkv + head * 192 + 64 + d;
                bf16x8 tvec;
#pragma unroll
                for (int e = 0; e < 8; e++) {
                    int tok = kk * 32 + lq * 8 + e;
                    tvec[e] = tok < NTOK ? vcol[(base + tok) * HQKV] : (short)0;
                }
                pb[j][kk] = tvec;
            }
#pragma unroll
        for (int i = 0; i < 4; i++)
#pragma unroll
            for (int j = 0; j < 4; j++) {
                o[i][j] = __builtin_amdgcn_mfma_f32_16x16x32_bf16(
                    pa[i][0], pb[j][0], fz, 0, 0, 0);
                o[i][j] = __builtin_amdgcn_mfma_f32_16x16x32_bf16(
                    pa[i][1], pb[j][1], o[i][j], 0, 0, 0);
            }
#pragma unroll
        for (int i = 0; i < 4; i++)
#pragma unroll
            for (int j = 0; j < 4; j++)
#pragma unroll
                for (int r = 0; r < 4; r++) {
                    int row = i * 16 + lq * 4 + r;
                    if (row < NTOK)
                        attn_out[(base + row) * DHID + head * 128 + half * 64 + j * 16 + lr] =
                            f2f8(o[i][j][r]);
                }
    }
}

extern "C" void kernel_launch(void* const* d_in, const int* in_sizes, int n_in,
                              void* d_out, int out_size, void* d_ws, size_t ws_size,
                              hipStream_t stream) {
    const float* x      = (const float*)d_in[0];
    const float* qkv_w  = (const float*)d_in[1];
    const float* qkv_b  = (const float*)d_in[2];
    const float* proj_w = (const float*)d_in[3];
    const float* proj_b = (const float*)d_in[4];
    const float* fc1_w  = (const float*)d_in[5];
    const float* fc1_b  = (const float*)d_in[6];
    const float* fc2_w  = (const float*)d_in[7];
    const float* fc2_b  = (const float*)d_in[8];
    const float* n1g    = (const float*)d_in[9];
    const float* n1b    = (const float*)d_in[10];
    const float* n2g    = (const float*)d_in[11];
    const float* n2b    = (const float*)d_in[12];
    const float* ls1    = (const float*)d_in[13];
    const float* ls2    = (const float*)d_in[14];
    const float* biases = (const float*)d_in[15];
    const int*   bidx   = (const int*)d_in[16];
    float* outp = (float*)d_out;

    char* ws = (char*)d_ws;
    u8* Wq = (u8*)ws; ws += 688128;
    u8* Wp = (u8*)ws; ws += 458752;
    u8* W1 = (u8*)ws; ws += 802816;
    u8* W2 = (u8*)ws; ws += 802816;
    float* bfull = (float*)ws; ws += (size_t)NHEAD * NTOK * NTOK * 4;
    const size_t fixed = 2752512 + (size_t)NHEAD * NTOK * NTOK * 4;

    // per-row intermediates: hbuf 448 + qkvb 3072 + attb 1024 = 4544 B
    int IC = 1024;
    while (IC > 128) {
        size_t Rr = (size_t)IC * NTOK;
        if (fixed + Rr * 4544ull <= ws_size) break;
        IC >>= 1;
    }
    const size_t R = (size_t)IC * NTOK;
    u8*    hbuf = (u8*)ws;    ws += R * CDIM;       // LN out fp8 (reused LN2)
    short* qkvb = (short*)ws; ws += R * HQKV * 2;   // bf16 (attn input)
    u8*    attb = (u8*)ws;    ws += R * DHID;       // attn out fp8
    u8*    gbuf = (u8*)qkvb;  // FC1 out fp8 [R,1792] overlays qkvb (dead by then)

    convert_w<<<3136, 256, 0, stream>>>(qkv_w, proj_w, fc1_w, fc2_w,
                                        Wq, Wp, W1, W2, biases, bidx, bfull);

    for (int c0 = 0; c0 < 1024; c0 += IC) {
        const float* xc = x + (size_t)c0 * NTOK * CDIM;
        float* oc = outp + (size_t)c0 * NTOK * CDIM;
        const int Ri = IC * NTOK;
        const int gy = (Ri + 255) / 256;

        ln_kernel<<<Ri / 4, 256, 0, stream>>>(xc, hbuf, n1g, n1b);
        gemm_bt<0><<<dim3(HQKV / 256, gy), 1024, 0, stream>>>(
            hbuf, Wq, qkv_b, nullptr, nullptr, nullptr, (void*)qkvb, Ri, HQKV, CDIM);
        attn_mfma<<<dim3(NHEAD, IC), 64, 0, stream>>>(qkvb, bfull, attb);
        // proj writes residual stream x + attn*ls1 straight into oc
        gemm_bt<2><<<dim3(2, gy), 1024, 0, stream>>>(
            attb, Wp, proj_b, ls1, xc, oc, nullptr, Ri, CDIM, DHID);
        ln_kernel<<<Ri / 4, 256, 0, stream>>>(oc, hbuf, n2g, n2b);
        gemm_bt<1><<<dim3(FHID / 256, gy), 1024, 0, stream>>>(
            hbuf, W1, fc1_b, nullptr, nullptr, nullptr, (void*)gbuf, Ri, FHID, CDIM);
        // fc2 in-place residual update: oc = oc + fc2(gbuf)*ls2
        gemm_bt<2><<<dim3(2, gy), 1024, 0, stream>>>(
            gbuf, W2, fc2_b, ls2, oc, oc, nullptr, Ri, CDIM, FHID);
    }
}

// Round 9
// 788.908 us; speedup vs baseline: 1.4710x; 1.2920x over previous
//
#include <hip/hip_runtime.h>
#include <hip/hip_bf16.h>
#include <hip/hip_fp8.h>

// Meta3D block: LN1 -> QKV -> MFMA-attn(+rel-pos bias) -> proj(+ls1 resid)
//               LN2 -> FC1+GELU -> FC2(+ls2 resid)
// B=1024 imgs, N=49 tok, C=448. GEMMs y = x @ W.T (NT).
// R10: fp8 128x128 tile, 4 waves, ring-3 counted vmcnt (R5's proven schedule),
// 24KB LDS -> 4 blocks/CU. Cross-round data: per-CU K-step delivery tracks
// blocks/CU (R3:5blk=14.6 B/cyc .. R9:1blk=5-9); volume tracks bytes (fp8
// halves). This config minimizes BOTH: vol 2.16GB + 4-block multiplexing.
// LDS panel layout [k-half][row] (16B units) -> frag b64 reads are 2-way
// bank-aliased = free (m136); R9's 29.5M conflicts came from lr*32 stride.
// EPI1 gelu: exact erf -> v*sigmoid(1.702v) (error << fp8 e4m3 quantization).

#define NTOK 49
#define CDIM 448
#define NHEAD 8
#define DHID 1024
#define HQKV 1536
#define FHID 1792
#define QK_SCALE 0.1767766952966369f
#define INV_SCALE 5.656854249492381f

typedef __attribute__((ext_vector_type(8))) short bf16x8;
typedef __attribute__((ext_vector_type(4))) float f32x4;
typedef unsigned int u32;
typedef unsigned char u8;

__device__ __forceinline__ short f2b(float f) {
    __hip_bfloat16 h = __float2bfloat16(f);
    return *reinterpret_cast<short*>(&h);
}
__device__ __forceinline__ u8 f2f8(float f) {
    __hip_fp8_e4m3 h(f);                 // OCP e4m3fn, saturating RNE
    return *reinterpret_cast<u8*>(&h);
}

// async global->LDS, 16B per lane; LDS dest = wave-uniform base + lane*16
__device__ __forceinline__ void gll16(const void* g, void* l) {
    __builtin_amdgcn_global_load_lds(
        (const __attribute__((address_space(1))) u32*)g,
        (__attribute__((address_space(3))) u32*)l, 16, 0, 0);
}

// ---------------- setup: weights fp32->fp8 + rel-pos bias expansion ----------------
__global__ __launch_bounds__(256) void convert_w(
    const float* __restrict__ s0, const float* __restrict__ s1,
    const float* __restrict__ s2, const float* __restrict__ s3,
    u8* __restrict__ d0, u8* __restrict__ d1,
    u8* __restrict__ d2, u8* __restrict__ d3,
    const float* __restrict__ biases, const int* __restrict__ bidx,
    float* __restrict__ bfull)
{
    int i = blockIdx.x * 256 + threadIdx.x;
    if (i < 688128) d0[i] = f2f8(s0[i]);       // qkv_w 1536x448
    if (i < 458752) d1[i] = f2f8(s1[i]);       // proj_w 448x1024
    if (i < 802816) { d2[i] = f2f8(s2[i]);     // fc1_w 1792x448
                      d3[i] = f2f8(s3[i]); }   // fc2_w 448x1792
    if (i < NHEAD * NTOK * NTOK) {             // bias -> full [8,49,49]
        int h = i / (NTOK * NTOK), p = i % (NTOK * NTOK);
        bfull[i] = biases[h * NTOK + bidx[p]];
    }
}

// ---------------- LayerNorm: fp32 -> fp8, one wave per 448-row ----------------
__global__ __launch_bounds__(256) void ln_kernel(
    const float* __restrict__ x, u8* __restrict__ out,
    const float* __restrict__ g, const float* __restrict__ b)
{
    int row = blockIdx.x * 4 + (threadIdx.x >> 6);
    int lane = threadIdx.x & 63;
    const float* xr = x + (size_t)row * CDIM;
    float v[7];
    float s = 0.f;
#pragma unroll
    for (int i = 0; i < 7; i++) { v[i] = xr[i * 64 + lane]; s += v[i]; }
#pragma unroll
    for (int o = 32; o > 0; o >>= 1) s += __shfl_xor(s, o, 64);
    float mean = s * (1.0f / 448.0f);
    float q = 0.f;
#pragma unroll
    for (int i = 0; i < 7; i++) { float d = v[i] - mean; q += d * d; }
#pragma unroll
    for (int o = 32; o > 0; o >>= 1) q += __shfl_xor(q, o, 64);
    float rstd = rsqrtf(q * (1.0f / 448.0f) + 1e-5f);
    u8* orow = out + (size_t)row * CDIM;
#pragma unroll
    for (int i = 0; i < 7; i++) {
        int c = i * 64 + lane;
        orow[c] = f2f8((v[i] - mean) * rstd * g[c] + b[c]);
    }
}

// ---------------- fp8 NT GEMM, 128x128 tile, BK=32, 3-buf ring distance 2 ----------------
// 4 waves (256 thr), wave grid 2x2, 64x64 out/wave (acc 4x4 f32x4 = 64 AGPR;
// + 52 VGPR = 116 <= 128 -> 4 waves/SIMD; LDS 24KB -> 4 blocks/CU).
// LDS: per buffer, 8 A panels + 8 B panels; panel = 16 rows x 32 k fp8 = 512B
// stored [k-half h][row r] in 16B units: byte = h*256 + r*16. Wave w stages
// A panels {2w,2w+1} + B panels {2w,2w+1} with ONE gll16 each (1KB: lane L ->
// panel L>>5, h=(L>>4)&1, r=L&15; global src row m0+(2w+(L>>5))*16+r, bytes
// k0+h*16 -- contiguous 16B). Frag b64 read: panel + (lq>>1)*256 + lr*16 +
// (lq&1)*8 -> per-phase stride 16B = 2-way bank alias = free (m136); R9's
// lr*32 layout was 4-way (29.5M conflict cycles, matched analytically).
// Ring: 3 buffers, distance 2; wait vmcnt(2) completes tile t, leaves tile
// t+1's 2 DMAs in flight across the raw s_barrier; stage tile t+2 after.
// EPI 0: out_bf16 = acc + bias[col]            (qkvb stays bf16 for attn)
// EPI 1: out_fp8  = gelu_fast(acc + bias[col])  (v*sigmoid(1.702v))
// EPI 2: out_f32  = resid[row,col] + (acc + bias[col]) * ls[col]  (may alias)
template <int EPI>
__global__ __launch_bounds__(256, 4) void gemm_bt(
    const u8* __restrict__ A,        // [M,K] fp8 (M % 128 == 0)
    const u8* __restrict__ W,        // [N,K] fp8 (rows clamped if N%128)
    const float* __restrict__ bias,  // [N]
    const float* __restrict__ ls,    // [N]   (EPI 2)
    const float* resid,              // [M,N] (EPI 2; may alias outF)
    float* outF,                     // (EPI 2)
    void* outX,                      // EPI 0: short*, EPI 1: u8*
    int M, int N, int K)
{
    __shared__ __align__(16) u8 sA[3][4096];
    __shared__ __align__(16) u8 sB[3][4096];
    const int tid = threadIdx.x;
    const int lane = tid & 63;
    const int w = tid >> 6;          // 0..3
    const int lr = lane & 15, lq = lane >> 4;

    // m204 bijective XCD swizzle
    const int gx = gridDim.x;
    const int nwg = gx * gridDim.y;
    const int lin = blockIdx.y * gx + blockIdx.x;
    const int q8 = nwg >> 3, r8 = nwg & 7;
    const int xcd = lin & 7, sub = lin >> 3;
    const int wg = (xcd < r8 ? xcd * (q8 + 1) : r8 * (q8 + 1) + (xcd - r8) * q8) + sub;
    const int m0 = (wg / gx) * 128;
    const int n0 = (wg % gx) * 128;

    // staging: lane L -> panel p=L>>5 (of wave's pair), h=(L>>4)&1, r=L&15
    const int sp = lane >> 5;
    const int sh = (lane >> 4) & 1;
    const int sr = lane & 15;
    int rA = m0 + (2 * w + sp) * 16 + sr;              // M%128==0: in range
    int rB = n0 + (2 * w + sp) * 16 + sr; rB = rB < N ? rB : N - 1;
    u32 oA = (u32)rA * (u32)K + (u32)(sh * 16);
    u32 oB = (u32)rB * (u32)K + (u32)(sh * 16);
    const int dst = w * 1024;        // wave's 2-panel slab byte offset

    const f32x4 fz = {0.f, 0.f, 0.f, 0.f};
    f32x4 acc[4][4];
#pragma unroll
    for (int i = 0; i < 4; i++)
#pragma unroll
        for (int j = 0; j < 4; j++) acc[i][j] = fz;

    // frag read base: wave's m-half/n-half + [h=lq>>1][r=lr] + (lq&1)*8
    const int rdA = (w & 1) * 2048 + (lq >> 1) * 256 + lr * 16 + (lq & 1) * 8;
    const int rdB = (w >> 1) * 2048 + (lq >> 1) * 256 + lr * 16 + (lq & 1) * 8;

    const int nt = K >> 5;   // 14 / 32 / 56
    // prologue: stage tiles 0,1
    gll16(A + oA, sA[0] + dst); gll16(W + oB, sB[0] + dst); oA += 32; oB += 32;
    gll16(A + oA, sA[1] + dst); gll16(W + oB, sB[1] + dst); oA += 32; oB += 32;

    int bc = 0;   // compute buffer
    int bs = 2;   // stage buffer
    for (int t = 0; t < nt; t++) {
        // tile t's 2 DMAs done; tile t+1's 2 stay in flight across the barrier
        if (t + 1 < nt) asm volatile("s_waitcnt vmcnt(2)" ::: "memory");
        else            asm volatile("s_waitcnt vmcnt(0)" ::: "memory");
        __builtin_amdgcn_s_barrier();
        if (t + 2 < nt) {
            gll16(A + oA, sA[bs] + dst);
            gll16(W + oB, sB[bs] + dst);
            oA += 32; oB += 32;
            bs = (bs == 2) ? 0 : bs + 1;
        }
        const u8* baseA = sA[bc] + rdA;
        const u8* baseB = sB[bc] + rdB;
        bc = (bc == 2) ? 0 : bc + 1;
        long af[4], bfr[4];
#pragma unroll
        for (int i = 0; i < 4; i++) af[i] = *(const long*)(baseA + i * 512);
#pragma unroll
        for (int j = 0; j < 4; j++) bfr[j] = *(const long*)(baseB + j * 512);
#pragma unroll
        for (int i = 0; i < 4; i++)
#pragma unroll
            for (int j = 0; j < 4; j++)
                acc[i][j] = __builtin_amdgcn_mfma_f32_16x16x32_fp8_fp8(
                    af[i], bfr[j], acc[i][j], 0, 0, 0);
    }

    const int wm = (w & 1) * 64, wn = (w >> 1) * 64;
    // C/D layout: col=lane&15, row=(lane>>4)*4+reg (shape-determined, m89/m101)
#pragma unroll
    for (int i = 0; i < 4; i++)
#pragma unroll
        for (int j = 0; j < 4; j++)
#pragma unroll
            for (int r = 0; r < 4; r++) {
                int row = m0 + wm + i * 16 + lq * 4 + r;
                int col = n0 + wn + j * 16 + lr;
                if (col < N) {
                    float v = acc[i][j][r] + bias[col];
                    if (EPI == 0) {
                        ((short*)outX)[(size_t)row * N + col] = f2b(v);
                    } else if (EPI == 1) {
                        // fast gelu: v*sigmoid(1.702v); err << fp8 e4m3 quant
                        float gl = v / (1.0f + __expf(-1.702f * v));
                        ((u8*)outX)[(size_t)row * N + col] = f2f8(gl);
                    } else {
                        outF[(size_t)row * N + col] =
                            resid[(size_t)row * N + col] + v * ls[col];
                    }
                }
            }
}

// ---------------- MFMA attention (bf16 internals): 1 wave per (image, head) ----------------
// qkv input bf16 (unchanged verified path); output store is fp8 (attb).
__global__ __launch_bounds__(64) void attn_mfma(
    const short* __restrict__ qkv,    // [R,1536] bf16; per-head 192 = q32|k32|v128
    const float* __restrict__ bfull,  // [8,49,49] fp32
    u8* __restrict__ attn_out)        // [R,1024] fp8
{
    __shared__ short sP[64 * 72];     // P bf16, row stride 144B (16B aligned)
    const int head = blockIdx.x;
    const size_t base = (size_t)blockIdx.y * NTOK;
    const int lane = threadIdx.x;
    const int lr = lane & 15, lq = lane >> 4;

    // C-init = bias/SCALE; mask cols>=49 with -1e30
    f32x4 sc[4][4];
#pragma unroll
    for (int i = 0; i < 4; i++)
#pragma unroll
        for (int j = 0; j < 4; j++)
#pragma unroll
            for (int r = 0; r < 4; r++) {
                int row = i * 16 + lq * 4 + r, col = j * 16 + lr;
                float v;
                if (col >= NTOK)      v = -1e30f;
                else if (row < NTOK)  v = bfull[head * (NTOK * NTOK) + row * NTOK + col] * INV_SCALE;
                else                  v = 0.f;
                sc[i][j][r] = v;
            }

    // Q/K fragments straight from global (k-contiguous 16B; rows clamped)
    bf16x8 qf[4], kf[4];
#pragma unroll
    for (int i = 0; i < 4; i++) {
        int r = i * 16 + lr; r = r < NTOK ? r : NTOK - 1;
        const short* rp = qkv + (base + r) * HQKV + head * 192;
        qf[i] = *(const bf16x8*)(rp + lq * 8);
        kf[i] = *(const bf16x8*)(rp + 32 + lq * 8);
    }
#pragma unroll
    for (int i = 0; i < 4; i++)
#pragma unroll
        for (int j = 0; j < 4; j++)
            sc[i][j] = __builtin_amdgcn_mfma_f32_16x16x32_bf16(
                qf[i], kf[j], sc[i][j], 0, 0, 0);

    // softmax over (j regs x 16 lanes) per output row; P -> sP as bf16
#pragma unroll
    for (int i = 0; i < 4; i++)
#pragma unroll
        for (int r = 0; r < 4; r++) {
            float s0 = sc[i][0][r] * QK_SCALE;
            float s1 = sc[i][1][r] * QK_SCALE;
            float s2 = sc[i][2][r] * QK_SCALE;
            float s3 = sc[i][3][r] * QK_SCALE;
            float m = fmaxf(fmaxf(s0, s1), fmaxf(s2, s3));
#pragma unroll
            for (int o = 1; o < 16; o <<= 1) m = fmaxf(m, __shfl_xor(m, o, 64));
            float e0 = __expf(s0 - m), e1 = __expf(s1 - m);
            float e2 = __expf(s2 - m), e3 = __expf(s3 - m);
            float l = e0 + e1 + e2 + e3;
#pragma unroll
            for (int o = 1; o < 16; o <<= 1) l += __shfl_xor(l, o, 64);
            float inv = 1.0f / l;
            short* pr = &sP[(i * 16 + lq * 4 + r) * 72];
            pr[lr]      = f2b(e0 * inv);
            pr[16 + lr] = f2b(e1 * inv);
            pr[32 + lr] = f2b(e2 * inv);
            pr[48 + lr] = f2b(e3 * inv);
        }
    // single wave: ds_write->ds_read ordered by lgkmcnt, no barrier needed

    // PV: A = P, B rows = V^T[d][tok] gathered from global (tok>=49 -> 0)
    bf16x8 pa[4][2];
#pragma unroll
    for (int i = 0; i < 4; i++)
#pragma unroll
        for (int kk = 0; kk < 2; kk++)
            pa[i][kk] = *(const bf16x8*)&sP[(i * 16 + lr) * 72 + kk * 32 + lq * 8];

#pragma unroll
    for (int half = 0; half < 2; half++) {
        const f32x4 fz = {0.f, 0.f, 0.f, 0.f};
        f32x4 o[4][4];
        bf16x8 pb[4][2];
#pragma unroll
        for (int j = 0; j < 4; j++)
#pragma unroll
            for (int kk = 0; kk < 2; kk++) {
                const int d = half * 64 + j * 16 + lr;
                const short* vcol = qkv + head * 192 + 64 + d;
                bf16x8 tvec;
#pragma unroll
                for (int e = 0; e < 8; e++) {
                    int tok = kk * 32 + lq * 8 + e;
                    tvec[e] = tok < NTOK ? vcol[(base + tok) * HQKV] : (short)0;
                }
                pb[j][kk] = tvec;
            }
#pragma unroll
        for (int i = 0; i < 4; i++)
#pragma unroll
            for (int j = 0; j < 4; j++) {
                o[i][j] = __builtin_amdgcn_mfma_f32_16x16x32_bf16(
                    pa[i][0], pb[j][0], fz, 0, 0, 0);
                o[i][j] = __builtin_amdgcn_mfma_f32_16x16x32_bf16(
                    pa[i][1], pb[j][1], o[i][j], 0, 0, 0);
            }
#pragma unroll
        for (int i = 0; i < 4; i++)
#pragma unroll
            for (int j = 0; j < 4; j++)
#pragma unroll
                for (int r = 0; r < 4; r++) {
                    int row = i * 16 + lq * 4 + r;
                    if (row < NTOK)
                        attn_out[(base + row) * DHID + head * 128 + half * 64 + j * 16 + lr] =
                            f2f8(o[i][j][r]);
                }
    }
}

extern "C" void kernel_launch(void* const* d_in, const int* in_sizes, int n_in,
                              void* d_out, int out_size, void* d_ws, size_t ws_size,
                              hipStream_t stream) {
    const float* x      = (const float*)d_in[0];
    const float* qkv_w  = (const float*)d_in[1];
    const float* qkv_b  = (const float*)d_in[2];
    const float* proj_w = (const float*)d_in[3];
    const float* proj_b = (const float*)d_in[4];
    const float* fc1_w  = (const float*)d_in[5];
    const float* fc1_b  = (const float*)d_in[6];
    const float* fc2_w  = (const float*)d_in[7];
    const float* fc2_b  = (const float*)d_in[8];
    const float* n1g    = (const float*)d_in[9];
    const float* n1b    = (const float*)d_in[10];
    const float* n2g    = (const float*)d_in[11];
    const float* n2b    = (const float*)d_in[12];
    const float* ls1    = (const float*)d_in[13];
    const float* ls2    = (const float*)d_in[14];
    const float* biases = (const float*)d_in[15];
    const int*   bidx   = (const int*)d_in[16];
    float* outp = (float*)d_out;

    char* ws = (char*)d_ws;
    u8* Wq = (u8*)ws; ws += 688128;
    u8* Wp = (u8*)ws; ws += 458752;
    u8* W1 = (u8*)ws; ws += 802816;
    u8* W2 = (u8*)ws; ws += 802816;
    float* bfull = (float*)ws; ws += (size_t)NHEAD * NTOK * NTOK * 4;
    const size_t fixed = 2752512 + (size_t)NHEAD * NTOK * NTOK * 4;

    // per-row intermediates: hbuf 448 + qkvb 3072 + attb 1024 = 4544 B
    int IC = 1024;
    while (IC > 128) {
        size_t Rr = (size_t)IC * NTOK;
        if (fixed + Rr * 4544ull <= ws_size) break;
        IC >>= 1;
    }
    const size_t R = (size_t)IC * NTOK;
    u8*    hbuf = (u8*)ws;    ws += R * CDIM;       // LN out fp8 (reused LN2)
    short* qkvb = (short*)ws; ws += R * HQKV * 2;   // bf16 (attn input)
    u8*    attb = (u8*)ws;    ws += R * DHID;       // attn out fp8
    u8*    gbuf = (u8*)qkvb;  // FC1 out fp8 [R,1792] overlays qkvb (dead by then)

    convert_w<<<3136, 256, 0, stream>>>(qkv_w, proj_w, fc1_w, fc2_w,
                                        Wq, Wp, W1, W2, biases, bidx, bfull);

    for (int c0 = 0; c0 < 1024; c0 += IC) {
        const float* xc = x + (size_t)c0 * NTOK * CDIM;
        float* oc = outp + (size_t)c0 * NTOK * CDIM;
        const int Ri = IC * NTOK;
        const int gy = (Ri + 127) / 128;

        ln_kernel<<<Ri / 4, 256, 0, stream>>>(xc, hbuf, n1g, n1b);
        gemm_bt<0><<<dim3(HQKV / 128, gy), 256, 0, stream>>>(
            hbuf, Wq, qkv_b, nullptr, nullptr, nullptr, (void*)qkvb, Ri, HQKV, CDIM);
        attn_mfma<<<dim3(NHEAD, IC), 64, 0, stream>>>(qkvb, bfull, attb);
        // proj writes residual stream x + attn*ls1 straight into oc
        gemm_bt<2><<<dim3(4, gy), 256, 0, stream>>>(
            attb, Wp, proj_b, ls1, xc, oc, nullptr, Ri, CDIM, DHID);
        ln_kernel<<<Ri / 4, 256, 0, stream>>>(oc, hbuf, n2g, n2b);
        gemm_bt<1><<<dim3(FHID / 128, gy), 256, 0, stream>>>(
            hbuf, W1, fc1_b, nullptr, nullptr, nullptr, (void*)gbuf, Ri, FHID, CDIM);
        // fc2 in-place residual update: oc = oc + fc2(gbuf)*ls2
        gemm_bt<2><<<dim3(4, gy), 256, 0, stream>>>(
            gbuf, W2, fc2_b, ls2, oc, oc, nullptr, Ri, CDIM, FHID);
    }
}

// Round 13
// 736.798 us; speedup vs baseline: 1.5751x; 1.0707x over previous
//
#include <hip/hip_runtime.h>
#include <hip/hip_bf16.h>
#include <hip/hip_fp8.h>

// Meta3D block: LN1 -> QKV -> MFMA-attn(+rel-pos bias) -> proj(+ls1 resid)
//               LN2 -> FC1+GELU -> FC2(+ls2 resid)
// B=1024 imgs, N=49 tok, C=448. GEMMs y = x @ W.T (NT).
// R11 (3rd resubmit; three GPUAcquisitionTimeouts -- broker capacity, not a
// kernel failure; acquisition precedes compile/run): panel-packed fp8
// operands. R10's [k-half][row] LDS layout was a real 4-way bank conflict
// (11.24M cycles, matched analytically). Conflict-free fp8 b64 frag read =
// addr const+lane*8, which needs LDS panel layout [k-oct][row].
// global_load_lds can't build that from row-major global (m104), so we store
// ALL GEMM operands panel-packed in GLOBAL (m173 pre-swizzle pattern): panel
// (pr,pk) = rows [pr*16,+16) x k [pk*32,+32) stored as 512B: off = q*128+r*8+b.
// DMA dest stays linear lane*16; frag reads + DMA writes both lane-monotonic.
// Producers all ours: convert_w (weights), ln (hbuf), attn store (attb),
// fc1 epilogue (gbuf). + T5 setprio around MFMA (4 independent blocks/CU =
// phase-diverse regime where setprio pays, unlike lockstep m190).

#define NTOK 49
#define CDIM 448
#define NHEAD 8
#define DHID 1024
#define HQKV 1536
#define FHID 1792
#define QK_SCALE 0.1767766952966369f
#define INV_SCALE 5.656854249492381f

typedef __attribute__((ext_vector_type(8))) short bf16x8;
typedef __attribute__((ext_vector_type(4))) float f32x4;
typedef unsigned int u32;
typedef unsigned char u8;

__device__ __forceinline__ short f2b(float f) {
    __hip_bfloat16 h = __float2bfloat16(f);
    return *reinterpret_cast<short*>(&h);
}
__device__ __forceinline__ u8 f2f8(float f) {
    __hip_fp8_e4m3 h(f);                 // OCP e4m3fn, saturating RNE
    return *reinterpret_cast<u8*>(&h);
}

// packed offset: operand [rows][K] fp8, nkp = K/32 panels per row-band
__device__ __forceinline__ u32 pack_off(int row, int k, int nkp) {
    return (u32)(((row >> 4) * nkp + (k >> 5)) << 9) +
           (u32)((((k & 31) >> 3) << 7) + ((row & 15) << 3) + (k & 7));
}

// async global->LDS, 16B per lane; LDS dest = wave-uniform base + lane*16
__device__ __forceinline__ void gll16(const void* g, void* l) {
    __builtin_amdgcn_global_load_lds(
        (const __attribute__((address_space(1))) u32*)g,
        (__attribute__((address_space(3))) u32*)l, 16, 0, 0);
}

// ---------------- setup: weights fp32 -> packed fp8 + bias expansion ----------------
__global__ __launch_bounds__(256) void convert_w(
    const float* __restrict__ s0, const float* __restrict__ s1,
    const float* __restrict__ s2, const float* __restrict__ s3,
    u8* __restrict__ d0, u8* __restrict__ d1,
    u8* __restrict__ d2, u8* __restrict__ d3,
    const float* __restrict__ biases, const int* __restrict__ bidx,
    float* __restrict__ bfull)
{
    int i = blockIdx.x * 256 + threadIdx.x;
    if (i < 688128) {                           // qkv_w 1536x448
        int n = i / 448, k = i - n * 448;
        d0[pack_off(n, k, 14)] = f2f8(s0[i]);
    }
    if (i < 458752) {                           // proj_w 448x1024
        int n = i >> 10, k = i & 1023;
        d1[pack_off(n, k, 32)] = f2f8(s1[i]);
    }
    if (i < 802816) {
        int n2 = i / 448, k2 = i - n2 * 448;    // fc1_w 1792x448
        d2[pack_off(n2, k2, 14)] = f2f8(s2[i]);
        int n3 = i / 1792, k3 = i - n3 * 1792;  // fc2_w 448x1792
        d3[pack_off(n3, k3, 56)] = f2f8(s3[i]);
    }
    if (i < NHEAD * NTOK * NTOK) {              // bias -> full [8,49,49]
        int h = i / (NTOK * NTOK), p = i % (NTOK * NTOK);
        bfull[i] = biases[h * NTOK + bidx[p]];
    }
}

// ---------------- LayerNorm: fp32 -> packed fp8 (nkp=14), one wave per row ----------------
__global__ __launch_bounds__(256) void ln_kernel(
    const float* __restrict__ x, u8* __restrict__ out,
    const float* __restrict__ g, const float* __restrict__ b)
{
    int row = blockIdx.x * 4 + (threadIdx.x >> 6);
    int lane = threadIdx.x & 63;
    const float* xr = x + (size_t)row * CDIM;
    float v[7];
    float s = 0.f;
#pragma unroll
    for (int i = 0; i < 7; i++) { v[i] = xr[i * 64 + lane]; s += v[i]; }
#pragma unroll
    for (int o = 32; o > 0; o >>= 1) s += __shfl_xor(s, o, 64);
    float mean = s * (1.0f / 448.0f);
    float q = 0.f;
#pragma unroll
    for (int i = 0; i < 7; i++) { float d = v[i] - mean; q += d * d; }
#pragma unroll
    for (int o = 32; o > 0; o >>= 1) q += __shfl_xor(q, o, 64);
    float rstd = rsqrtf(q * (1.0f / 448.0f) + 1e-5f);
#pragma unroll
    for (int i = 0; i < 7; i++) {
        int c = i * 64 + lane;
        out[pack_off(row, c, 14)] = f2f8((v[i] - mean) * rstd * g[c] + b[c]);
    }
}

// ---------------- fp8 NT GEMM, 128x128 tile, BK=32, 3-buf ring, packed operands ----------------
// 4 waves, wave grid 2x2, 64x64 out/wave (acc 4x4 f32x4 = 64 AGPR; ~112 unified
// regs -> 4 waves/SIMD; LDS 24KB -> 4 blocks/CU).
// LDS buffer = 8 A panels + 8 B panels, 512B each, packed [k-oct][row]. Wave w
// stages panels {2w,2w+1} of A and B, ONE gll16 each: lane L reads global
// 16B chunk (L&31)*16 of panel (2w+(L>>5)); panels are 512B-contiguous in
// global, so per-lane addresses are exact (global src is per-lane, m173).
// Frag b64 read addr = const + lane*8 -> contiguous 512B/wave, ZERO conflicts
// (R3-verified pattern). DMA dest = base + lane*16, linear.
// Ring: 3 buffers, distance 2, counted vmcnt(2) (R5/R10 proven invariant).
// EPI 0: out_bf16 row-major = acc + bias[col]      (qkvb for attn)
// EPI 1: out_fp8 PACKED(nkp=N/32) = gelu_fast(acc + bias[col])
// EPI 2: out_f32 row-major = resid + (acc+bias)*ls  (resid may alias outF)
template <int EPI>
__global__ __launch_bounds__(256, 4) void gemm_bt(
    const u8* __restrict__ A,        // [M,K] fp8 PACKED (M % 128 == 0)
    const u8* __restrict__ W,        // [N,K] fp8 PACKED (panels clamped if N%128)
    const float* __restrict__ bias,  // [N]
    const float* __restrict__ ls,    // [N]   (EPI 2)
    const float* resid,              // [M,N] (EPI 2; may alias outF)
    float* outF,                     // (EPI 2)
    void* outX,                      // EPI 0: short*, EPI 1: u8*
    int M, int N, int K)
{
    __shared__ __align__(16) u8 sA[3][4096];
    __shared__ __align__(16) u8 sB[3][4096];
    const int tid = threadIdx.x;
    const int lane = tid & 63;
    const int w = tid >> 6;          // 0..3
    const int lr = lane & 15, lq = lane >> 4;

    // m204 bijective XCD swizzle
    const int gx = gridDim.x;
    const int nwg = gx * gridDim.y;
    const int lin = blockIdx.y * gx + blockIdx.x;
    const int q8 = nwg >> 3, r8 = nwg & 7;
    const int xcd = lin & 7, sub = lin >> 3;
    const int wg = (xcd < r8 ? xcd * (q8 + 1) : r8 * (q8 + 1) + (xcd - r8) * q8) + sub;
    const int m0 = (wg / gx) * 128;
    const int n0 = (wg % gx) * 128;

    const int nkp = K >> 5;
    // staging: wave w -> panels {2w, 2w+1}; lane L -> panel 2w+(L>>5), chunk (L&31)*16
    const int maxpB = (N >> 4) - 1;
    int prA = (m0 >> 4) + 2 * w + (lane >> 5);            // M%128==0: valid
    int prB = (n0 >> 4) + 2 * w + (lane >> 5);
    prB = prB < maxpB ? prB : maxpB;                      // clamp at panel level
    u32 oA = (u32)(prA * nkp) * 512u + (u32)((lane & 31) * 16);
    u32 oB = (u32)(prB * nkp) * 512u + (u32)((lane & 31) * 16);
    const int dst = w * 1024;        // wave's 2-panel slab byte offset in LDS

    const f32x4 fz = {0.f, 0.f, 0.f, 0.f};
    f32x4 acc[4][4];
#pragma unroll
    for (int i = 0; i < 4; i++)
#pragma unroll
        for (int j = 0; j < 4; j++) acc[i][j] = fz;

    // frag read base: addr = base + lane*8 (monotonic -> conflict-free)
    const int rdA = (w & 1) * 2048 + lq * 128 + lr * 8;
    const int rdB = (w >> 1) * 2048 + lq * 128 + lr * 8;

    const int nt = K >> 5;   // 14 / 32 / 56
    // prologue: stage tiles 0,1
    gll16(A + oA, sA[0] + dst); gll16(W + oB, sB[0] + dst); oA += 512; oB += 512;
    gll16(A + oA, sA[1] + dst); gll16(W + oB, sB[1] + dst); oA += 512; oB += 512;

    int bc = 0;   // compute buffer
    int bs = 2;   // stage buffer
    for (int t = 0; t < nt; t++) {
        // tile t's 2 DMAs done; tile t+1's 2 stay in flight across the barrier
        if (t + 1 < nt) asm volatile("s_waitcnt vmcnt(2)" ::: "memory");
        else            asm volatile("s_waitcnt vmcnt(0)" ::: "memory");
        __builtin_amdgcn_s_barrier();
        if (t + 2 < nt) {
            gll16(A + oA, sA[bs] + dst);
            gll16(W + oB, sB[bs] + dst);
            oA += 512; oB += 512;
            bs = (bs == 2) ? 0 : bs + 1;
        }
        const u8* baseA = sA[bc] + rdA;
        const u8* baseB = sB[bc] + rdB;
        bc = (bc == 2) ? 0 : bc + 1;
        long af[4], bfr[4];
#pragma unroll
        for (int i = 0; i < 4; i++) af[i] = *(const long*)(baseA + i * 512);
#pragma unroll
        for (int j = 0; j < 4; j++) bfr[j] = *(const long*)(baseB + j * 512);
        __builtin_amdgcn_s_setprio(1);
#pragma unroll
        for (int i = 0; i < 4; i++)
#pragma unroll
            for (int j = 0; j < 4; j++)
                acc[i][j] = __builtin_amdgcn_mfma_f32_16x16x32_fp8_fp8(
                    af[i], bfr[j], acc[i][j], 0, 0, 0);
        __builtin_amdgcn_s_setprio(0);
    }

    const int wm = (w & 1) * 64, wn = (w >> 1) * 64;
    // C/D layout: col=lane&15, row=(lane>>4)*4+reg (shape-determined, m89/m101)
#pragma unroll
    for (int i = 0; i < 4; i++)
#pragma unroll
        for (int j = 0; j < 4; j++)
#pragma unroll
            for (int r = 0; r < 4; r++) {
                int row = m0 + wm + i * 16 + lq * 4 + r;
                int col = n0 + wn + j * 16 + lr;
                if (col < N) {
                    float v = acc[i][j][r] + bias[col];
                    if (EPI == 0) {
                        ((short*)outX)[(size_t)row * N + col] = f2b(v);
                    } else if (EPI == 1) {
                        // fast gelu: v*sigmoid(1.702v); err << fp8 e4m3 quant
                        float gl = v / (1.0f + __expf(-1.702f * v));
                        ((u8*)outX)[pack_off(row, col, N >> 5)] = f2f8(gl);
                    } else {
                        outF[(size_t)row * N + col] =
                            resid[(size_t)row * N + col] + v * ls[col];
                    }
                }
            }
}

// ---------------- MFMA attention (bf16 internals): 1 wave per (image, head) ----------------
// qkv input bf16 row-major (unchanged verified path); output store packed fp8
// (attb feeds proj's A, K=1024 -> nkp=32).
__global__ __launch_bounds__(64) void attn_mfma(
    const short* __restrict__ qkv,    // [R,1536] bf16; per-head 192 = q32|k32|v128
    const float* __restrict__ bfull,  // [8,49,49] fp32
    u8* __restrict__ attn_out)        // [R,1024] fp8 PACKED nkp=32
{
    __shared__ short sP[64 * 72];     // P bf16, row stride 144B (16B aligned)
    const int head = blockIdx.x;
    const size_t base = (size_t)blockIdx.y * NTOK;
    const int lane = threadIdx.x;
    const int lr = lane & 15, lq = lane >> 4;

    // C-init = bias/SCALE; mask cols>=49 with -1e30
    f32x4 sc[4][4];
#pragma unroll
    for (int i = 0; i < 4; i++)
#pragma unroll
        for (int j = 0; j < 4; j++)
#pragma unroll
            for (int r = 0; r < 4; r++) {
                int row = i * 16 + lq * 4 + r, col = j * 16 + lr;
                float v;
                if (col >= NTOK)      v = -1e30f;
                else if (row < NTOK)  v = bfull[head * (NTOK * NTOK) + row * NTOK + col] * INV_SCALE;
                else                  v = 0.f;
                sc[i][j][r] = v;
            }

    // Q/K fragments straight from global (k-contiguous 16B; rows clamped)
    bf16x8 qf[4], kf[4];
#pragma unroll
    for (int i = 0; i < 4; i++) {
        int r = i * 16 + lr; r = r < NTOK ? r : NTOK - 1;
        const short* rp = qkv + (base + r) * HQKV + head * 192;
        qf[i] = *(const bf16x8*)(rp + lq * 8);
        kf[i] = *(const bf16x8*)(rp + 32 + lq * 8);
    }
#pragma unroll
    for (int i = 0; i < 4; i++)
#pragma unroll
        for (int j = 0; j < 4; j++)
            sc[i][j] = __builtin_amdgcn_mfma_f32_16x16x32_bf16(
                qf[i], kf[j], sc[i][j], 0, 0, 0);

    // softmax over (j regs x 16 lanes) per output row; P -> sP as bf16
#pragma unroll
    for (int i = 0; i < 4; i++)
#pragma unroll
        for (int r = 0; r < 4; r++) {
            float s0 = sc[i][0][r] * QK_SCALE;
            float s1 = sc[i][1][r] * QK_SCALE;
            float s2 = sc[i][2][r] * QK_SCALE;
            float s3 = sc[i][3][r] * QK_SCALE;
            float m = fmaxf(fmaxf(s0, s1), fmaxf(s2, s3));
#pragma unroll
            for (int o = 1; o < 16; o <<= 1) m = fmaxf(m, __shfl_xor(m, o, 64));
            float e0 = __expf(s0 - m), e1 = __expf(s1 - m);
            float e2 = __expf(s2 - m), e3 = __expf(s3 - m);
            float l = e0 + e1 + e2 + e3;
#pragma unroll
            for (int o = 1; o < 16; o <<= 1) l += __shfl_xor(l, o, 64);
            float inv = 1.0f / l;
            short* pr = &sP[(i * 16 + lq * 4 + r) * 72];
            pr[lr]      = f2b(e0 * inv);
            pr[16 + lr] = f2b(e1 * inv);
            pr[32 + lr] = f2b(e2 * inv);
            pr[48 + lr] = f2b(e3 * inv);
        }
    // single wave: ds_write->ds_read ordered by lgkmcnt, no barrier needed

    // PV: A = P, B rows = V^T[d][tok] gathered from global (tok>=49 -> 0)
    bf16x8 pa[4][2];
#pragma unroll
    for (int i = 0; i < 4; i++)
#pragma unroll
        for (int kk = 0; kk < 2; kk++)
            pa[i][kk] = *(const bf16x8*)&sP[(i * 16 + lr) * 72 + kk * 32 + lq * 8];

#pragma unroll
    for (int half = 0; half < 2; half++) {
        const f32x4 fz = {0.f, 0.f, 0.f, 0.f};
        f32x4 o[4][4];
        bf16x8 pb[4][2];
#pragma unroll
        for (int j = 0; j < 4; j++)
#pragma unroll
            for (int kk = 0; kk < 2; kk++) {
                const int d = half * 64 + j * 16 + lr;
                const short* vcol = qkv + head * 192 + 64 + d;
                bf16x8 tvec;
#pragma unroll
                for (int e = 0; e < 8; e++) {
                    int tok = kk * 32 + lq * 8 + e;
                    tvec[e] = tok < NTOK ? vcol[(base + tok) * HQKV] : (short)0;
                }
                pb[j][kk] = tvec;
            }
#pragma unroll
        for (int i = 0; i < 4; i++)
#pragma unroll
            for (int j = 0; j < 4; j++) {
                o[i][j] = __builtin_amdgcn_mfma_f32_16x16x32_bf16(
                    pa[i][0], pb[j][0], fz, 0, 0, 0);
                o[i][j] = __builtin_amdgcn_mfma_f32_16x16x32_bf16(
                    pa[i][1], pb[j][1], o[i][j], 0, 0, 0);
            }
#pragma unroll
        for (int i = 0; i < 4; i++)
#pragma unroll
            for (int j = 0; j < 4; j++)
#pragma unroll
                for (int r = 0; r < 4; r++) {
                    int row = i * 16 + lq * 4 + r;
                    if (row < NTOK)
                        attn_out[pack_off((int)(base + row),
                                          head * 128 + half * 64 + j * 16 + lr, 32)] =
                            f2f8(o[i][j][r]);
                }
    }
}

extern "C" void kernel_launch(void* const* d_in, const int* in_sizes, int n_in,
                              void* d_out, int out_size, void* d_ws, size_t ws_size,
                              hipStream_t stream) {
    const float* x      = (const float*)d_in[0];
    const float* qkv_w  = (const float*)d_in[1];
    const float* qkv_b  = (const float*)d_in[2];
    const float* proj_w = (const float*)d_in[3];
    const float* proj_b = (const float*)d_in[4];
    const float* fc1_w  = (const float*)d_in[5];
    const float* fc1_b  = (const float*)d_in[6];
    const float* fc2_w  = (const float*)d_in[7];
    const float* fc2_b  = (const float*)d_in[8];
    const float* n1g    = (const float*)d_in[9];
    const float* n1b    = (const float*)d_in[10];
    const float* n2g    = (const float*)d_in[11];
    const float* n2b    = (const float*)d_in[12];
    const float* ls1    = (const float*)d_in[13];
    const float* ls2    = (const float*)d_in[14];
    const float* biases = (const float*)d_in[15];
    const int*   bidx   = (const int*)d_in[16];
    float* outp = (float*)d_out;

    char* ws = (char*)d_ws;
    u8* Wq = (u8*)ws; ws += 688128;
    u8* Wp = (u8*)ws; ws += 458752;
    u8* W1 = (u8*)ws; ws += 802816;
    u8* W2 = (u8*)ws; ws += 802816;
    float* bfull = (float*)ws; ws += (size_t)NHEAD * NTOK * NTOK * 4;
    const size_t fixed = 2752512 + (size_t)NHEAD * NTOK * NTOK * 4;

    // per-row intermediates: hbuf 448 + qkvb 3072 + attb 1024 = 4544 B
    int IC = 1024;
    while (IC > 128) {
        size_t Rr = (size_t)IC * NTOK;
        if (fixed + Rr * 4544ull <= ws_size) break;
        IC >>= 1;
    }
    const size_t R = (size_t)IC * NTOK;
    u8*    hbuf = (u8*)ws;    ws += R * CDIM;       // LN out fp8 packed (reused LN2)
    short* qkvb = (short*)ws; ws += R * HQKV * 2;   // bf16 row-major (attn input)
    u8*    attb = (u8*)ws;    ws += R * DHID;       // attn out fp8 packed
    u8*    gbuf = (u8*)qkvb;  // FC1 out fp8 packed [R,1792] overlays qkvb

    convert_w<<<3136, 256, 0, stream>>>(qkv_w, proj_w, fc1_w, fc2_w,
                                        Wq, Wp, W1, W2, biases, bidx, bfull);

    for (int c0 = 0; c0 < 1024; c0 += IC) {
        const float* xc = x + (size_t)c0 * NTOK * CDIM;
        float* oc = outp + (size_t)c0 * NTOK * CDIM;
        const int Ri = IC * NTOK;
        const int gy = (Ri + 127) / 128;

        ln_kernel<<<Ri / 4, 256, 0, stream>>>(xc, hbuf, n1g, n1b);
        gemm_bt<0><<<dim3(HQKV / 128, gy), 256, 0, stream>>>(
            hbuf, Wq, qkv_b, nullptr, nullptr, nullptr, (void*)qkvb, Ri, HQKV, CDIM);
        attn_mfma<<<dim3(NHEAD, IC), 64, 0, stream>>>(qkvb, bfull, attb);
        // proj writes residual stream x + attn*ls1 straight into oc
        gemm_bt<2><<<dim3(4, gy), 256, 0, stream>>>(
            attb, Wp, proj_b, ls1, xc, oc, nullptr, Ri, CDIM, DHID);
        ln_kernel<<<Ri / 4, 256, 0, stream>>>(oc, hbuf, n2g, n2b);
        gemm_bt<1><<<dim3(FHID / 128, gy), 256, 0, stream>>>(
            hbuf, W1, fc1_b, nullptr, nullptr, nullptr, (void*)gbuf, Ri, FHID, CDIM);
        // fc2 in-place residual update: oc = oc + fc2(gbuf)*ls2
        gemm_bt<2><<<dim3(4, gy), 256, 0, stream>>>(
            gbuf, W2, fc2_b, ls2, oc, oc, nullptr, Ri, CDIM, FHID);
    }
}

// Round 14
// 722.616 us; speedup vs baseline: 1.6060x; 1.0196x over previous
//
#include <hip/hip_runtime.h>
#include <hip/hip_bf16.h>
#include <hip/hip_fp8.h>

// Meta3D block: LN1 -> QKV -> MFMA-attn(+rel-pos bias) -> proj(+ls1 resid)
//               LN2 -> FC1+GELU -> FC2(+ls2 resid)
// B=1024 imgs, N=49 tok, C=448. GEMMs y = x @ W.T (NT).
// R12: attn is now the top dispatch (169.8us; MfmaUtil 2.5%, Occ 22%, HBM 12%
// -> latency-bound, occupancy-starved). The (img,head) work is row-separable:
// QK A-side, softmax, P-transpose, PV output are all private to a 16-query-row
// group; only K/V (B-sides) are shared (small, L1-absorbed when duplicated).
// So: block = 4 waves, wave wi owns query rows wi*16..+15. Serial chain /4,
// wave-slots allow 8 blocks/CU = 32 waves/CU. sP is per-wave -> still ZERO
// barriers. GEMM/LN/convert identical to R11 (conflict-free packed fp8).

#define NTOK 49
#define CDIM 448
#define NHEAD 8
#define DHID 1024
#define HQKV 1536
#define FHID 1792
#define QK_SCALE 0.1767766952966369f
#define INV_SCALE 5.656854249492381f

typedef __attribute__((ext_vector_type(8))) short bf16x8;
typedef __attribute__((ext_vector_type(4))) float f32x4;
typedef unsigned int u32;
typedef unsigned char u8;

__device__ __forceinline__ short f2b(float f) {
    __hip_bfloat16 h = __float2bfloat16(f);
    return *reinterpret_cast<short*>(&h);
}
__device__ __forceinline__ u8 f2f8(float f) {
    __hip_fp8_e4m3 h(f);                 // OCP e4m3fn, saturating RNE
    return *reinterpret_cast<u8*>(&h);
}

// packed offset: operand [rows][K] fp8, nkp = K/32 panels per row-band
__device__ __forceinline__ u32 pack_off(int row, int k, int nkp) {
    return (u32)(((row >> 4) * nkp + (k >> 5)) << 9) +
           (u32)((((k & 31) >> 3) << 7) + ((row & 15) << 3) + (k & 7));
}

// async global->LDS, 16B per lane; LDS dest = wave-uniform base + lane*16
__device__ __forceinline__ void gll16(const void* g, void* l) {
    __builtin_amdgcn_global_load_lds(
        (const __attribute__((address_space(1))) u32*)g,
        (__attribute__((address_space(3))) u32*)l, 16, 0, 0);
}

// ---------------- setup: weights fp32 -> packed fp8 + bias expansion ----------------
__global__ __launch_bounds__(256) void convert_w(
    const float* __restrict__ s0, const float* __restrict__ s1,
    const float* __restrict__ s2, const float* __restrict__ s3,
    u8* __restrict__ d0, u8* __restrict__ d1,
    u8* __restrict__ d2, u8* __restrict__ d3,
    const float* __restrict__ biases, const int* __restrict__ bidx,
    float* __restrict__ bfull)
{
    int i = blockIdx.x * 256 + threadIdx.x;
    if (i < 688128) {                           // qkv_w 1536x448
        int n = i / 448, k = i - n * 448;
        d0[pack_off(n, k, 14)] = f2f8(s0[i]);
    }
    if (i < 458752) {                           // proj_w 448x1024
        int n = i >> 10, k = i & 1023;
        d1[pack_off(n, k, 32)] = f2f8(s1[i]);
    }
    if (i < 802816) {
        int n2 = i / 448, k2 = i - n2 * 448;    // fc1_w 1792x448
        d2[pack_off(n2, k2, 14)] = f2f8(s2[i]);
        int n3 = i / 1792, k3 = i - n3 * 1792;  // fc2_w 448x1792
        d3[pack_off(n3, k3, 56)] = f2f8(s3[i]);
    }
    if (i < NHEAD * NTOK * NTOK) {              // bias -> full [8,49,49]
        int h = i / (NTOK * NTOK), p = i % (NTOK * NTOK);
        bfull[i] = biases[h * NTOK + bidx[p]];
    }
}

// ---------------- LayerNorm: fp32 -> packed fp8 (nkp=14), one wave per row ----------------
__global__ __launch_bounds__(256) void ln_kernel(
    const float* __restrict__ x, u8* __restrict__ out,
    const float* __restrict__ g, const float* __restrict__ b)
{
    int row = blockIdx.x * 4 + (threadIdx.x >> 6);
    int lane = threadIdx.x & 63;
    const float* xr = x + (size_t)row * CDIM;
    float v[7];
    float s = 0.f;
#pragma unroll
    for (int i = 0; i < 7; i++) { v[i] = xr[i * 64 + lane]; s += v[i]; }
#pragma unroll
    for (int o = 32; o > 0; o >>= 1) s += __shfl_xor(s, o, 64);
    float mean = s * (1.0f / 448.0f);
    float q = 0.f;
#pragma unroll
    for (int i = 0; i < 7; i++) { float d = v[i] - mean; q += d * d; }
#pragma unroll
    for (int o = 32; o > 0; o >>= 1) q += __shfl_xor(q, o, 64);
    float rstd = rsqrtf(q * (1.0f / 448.0f) + 1e-5f);
#pragma unroll
    for (int i = 0; i < 7; i++) {
        int c = i * 64 + lane;
        out[pack_off(row, c, 14)] = f2f8((v[i] - mean) * rstd * g[c] + b[c]);
    }
}

// ---------------- fp8 NT GEMM, 128x128 tile, BK=32, 3-buf ring, packed operands ----------------
// (identical to R11 -- conflict-free [k-oct][row] packed layout, ring-3
// counted vmcnt, setprio around MFMA, 4 blocks/CU)
template <int EPI>
__global__ __launch_bounds__(256, 4) void gemm_bt(
    const u8* __restrict__ A,        // [M,K] fp8 PACKED (M % 128 == 0)
    const u8* __restrict__ W,        // [N,K] fp8 PACKED (panels clamped if N%128)
    const float* __restrict__ bias,  // [N]
    const float* __restrict__ ls,    // [N]   (EPI 2)
    const float* resid,              // [M,N] (EPI 2; may alias outF)
    float* outF,                     // (EPI 2)
    void* outX,                      // EPI 0: short*, EPI 1: u8*
    int M, int N, int K)
{
    __shared__ __align__(16) u8 sA[3][4096];
    __shared__ __align__(16) u8 sB[3][4096];
    const int tid = threadIdx.x;
    const int lane = tid & 63;
    const int w = tid >> 6;          // 0..3
    const int lr = lane & 15, lq = lane >> 4;

    // m204 bijective XCD swizzle
    const int gx = gridDim.x;
    const int nwg = gx * gridDim.y;
    const int lin = blockIdx.y * gx + blockIdx.x;
    const int q8 = nwg >> 3, r8 = nwg & 7;
    const int xcd = lin & 7, sub = lin >> 3;
    const int wg = (xcd < r8 ? xcd * (q8 + 1) : r8 * (q8 + 1) + (xcd - r8) * q8) + sub;
    const int m0 = (wg / gx) * 128;
    const int n0 = (wg % gx) * 128;

    const int nkp = K >> 5;
    // staging: wave w -> panels {2w, 2w+1}; lane L -> panel 2w+(L>>5), chunk (L&31)*16
    const int maxpB = (N >> 4) - 1;
    int prA = (m0 >> 4) + 2 * w + (lane >> 5);            // M%128==0: valid
    int prB = (n0 >> 4) + 2 * w + (lane >> 5);
    prB = prB < maxpB ? prB : maxpB;                      // clamp at panel level
    u32 oA = (u32)(prA * nkp) * 512u + (u32)((lane & 31) * 16);
    u32 oB = (u32)(prB * nkp) * 512u + (u32)((lane & 31) * 16);
    const int dst = w * 1024;        // wave's 2-panel slab byte offset in LDS

    const f32x4 fz = {0.f, 0.f, 0.f, 0.f};
    f32x4 acc[4][4];
#pragma unroll
    for (int i = 0; i < 4; i++)
#pragma unroll
        for (int j = 0; j < 4; j++) acc[i][j] = fz;

    // frag read base: addr = base + lane*8 (monotonic -> conflict-free)
    const int rdA = (w & 1) * 2048 + lq * 128 + lr * 8;
    const int rdB = (w >> 1) * 2048 + lq * 128 + lr * 8;

    const int nt = K >> 5;   // 14 / 32 / 56
    // prologue: stage tiles 0,1
    gll16(A + oA, sA[0] + dst); gll16(W + oB, sB[0] + dst); oA += 512; oB += 512;
    gll16(A + oA, sA[1] + dst); gll16(W + oB, sB[1] + dst); oA += 512; oB += 512;

    int bc = 0;   // compute buffer
    int bs = 2;   // stage buffer
    for (int t = 0; t < nt; t++) {
        // tile t's 2 DMAs done; tile t+1's 2 stay in flight across the barrier
        if (t + 1 < nt) asm volatile("s_waitcnt vmcnt(2)" ::: "memory");
        else            asm volatile("s_waitcnt vmcnt(0)" ::: "memory");
        __builtin_amdgcn_s_barrier();
        if (t + 2 < nt) {
            gll16(A + oA, sA[bs] + dst);
            gll16(W + oB, sB[bs] + dst);
            oA += 512; oB += 512;
            bs = (bs == 2) ? 0 : bs + 1;
        }
        const u8* baseA = sA[bc] + rdA;
        const u8* baseB = sB[bc] + rdB;
        bc = (bc == 2) ? 0 : bc + 1;
        long af[4], bfr[4];
#pragma unroll
        for (int i = 0; i < 4; i++) af[i] = *(const long*)(baseA + i * 512);
#pragma unroll
        for (int j = 0; j < 4; j++) bfr[j] = *(const long*)(baseB + j * 512);
        __builtin_amdgcn_s_setprio(1);
#pragma unroll
        for (int i = 0; i < 4; i++)
#pragma unroll
            for (int j = 0; j < 4; j++)
                acc[i][j] = __builtin_amdgcn_mfma_f32_16x16x32_fp8_fp8(
                    af[i], bfr[j], acc[i][j], 0, 0, 0);
        __builtin_amdgcn_s_setprio(0);
    }

    const int wm = (w & 1) * 64, wn = (w >> 1) * 64;
    // C/D layout: col=lane&15, row=(lane>>4)*4+reg (shape-determined, m89/m101)
#pragma unroll
    for (int i = 0; i < 4; i++)
#pragma unroll
        for (int j = 0; j < 4; j++)
#pragma unroll
            for (int r = 0; r < 4; r++) {
                int row = m0 + wm + i * 16 + lq * 4 + r;
                int col = n0 + wn + j * 16 + lr;
                if (col < N) {
                    float v = acc[i][j][r] + bias[col];
                    if (EPI == 0) {
                        ((short*)outX)[(size_t)row * N + col] = f2b(v);
                    } else if (EPI == 1) {
                        // fast gelu: v*sigmoid(1.702v); err << fp8 e4m3 quant
                        float gl = v / (1.0f + __expf(-1.702f * v));
                        ((u8*)outX)[pack_off(row, col, N >> 5)] = f2f8(gl);
                    } else {
                        outF[(size_t)row * N + col] =
                            resid[(size_t)row * N + col] + v * ls[col];
                    }
                }
            }
}

// ---------------- MFMA attention: 4 waves per (image, head) ----------------
// Wave wi owns query rows wi*16..wi*16+15. Row-private work (QK A-side,
// softmax, P-transpose via per-wave sP slab, PV output) needs no cross-wave
// sync; K and V fragments are duplicated per wave (12.5KB/block -> L1).
// qkv input bf16 row-major; output store packed fp8 (attb, K=1024, nkp=32).
__global__ __launch_bounds__(256) void attn_mfma(
    const short* __restrict__ qkv,    // [R,1536] bf16; per-head 192 = q32|k32|v128
    const float* __restrict__ bfull,  // [8,49,49] fp32
    u8* __restrict__ attn_out)        // [R,1024] fp8 PACKED nkp=32
{
    __shared__ short sP[4][16 * 72];  // per-wave: 16 P-rows, stride 72 shorts
    const int head = blockIdx.x;
    const size_t base = (size_t)blockIdx.y * NTOK;
    const int tid = threadIdx.x;
    const int lane = tid & 63;
    const int wi = tid >> 6;          // wave = query-row group i
    const int lr = lane & 15, lq = lane >> 4;

    // C-init = bias/SCALE for own 16 rows; mask cols>=49 with -1e30
    f32x4 sc[4];
#pragma unroll
    for (int j = 0; j < 4; j++)
#pragma unroll
        for (int r = 0; r < 4; r++) {
            int row = wi * 16 + lq * 4 + r, col = j * 16 + lr;
            float v;
            if (col >= NTOK)      v = -1e30f;
            else if (row < NTOK)  v = bfull[head * (NTOK * NTOK) + row * NTOK + col] * INV_SCALE;
            else                  v = 0.f;
            sc[j][r] = v;
        }

    // Q frag (own rows) + all 4 K frags straight from global (rows clamped)
    bf16x8 qf, kf[4];
    {
        int r = wi * 16 + lr; r = r < NTOK ? r : NTOK - 1;
        qf = *(const bf16x8*)(qkv + (base + r) * HQKV + head * 192 + lq * 8);
    }
#pragma unroll
    for (int j = 0; j < 4; j++) {
        int r = j * 16 + lr; r = r < NTOK ? r : NTOK - 1;
        kf[j] = *(const bf16x8*)(qkv + (base + r) * HQKV + head * 192 + 32 + lq * 8);
    }
#pragma unroll
    for (int j = 0; j < 4; j++)
        sc[j] = __builtin_amdgcn_mfma_f32_16x16x32_bf16(qf, kf[j], sc[j], 0, 0, 0);

    // softmax for own 4 (lq-interleaved) row quads; P -> own sP slab as bf16
#pragma unroll
    for (int r = 0; r < 4; r++) {
        float s0 = sc[0][r] * QK_SCALE;
        float s1 = sc[1][r] * QK_SCALE;
        float s2 = sc[2][r] * QK_SCALE;
        float s3 = sc[3][r] * QK_SCALE;
        float m = fmaxf(fmaxf(s0, s1), fmaxf(s2, s3));
#pragma unroll
        for (int o = 1; o < 16; o <<= 1) m = fmaxf(m, __shfl_xor(m, o, 64));
        float e0 = __expf(s0 - m), e1 = __expf(s1 - m);
        float e2 = __expf(s2 - m), e3 = __expf(s3 - m);
        float l = e0 + e1 + e2 + e3;
#pragma unroll
        for (int o = 1; o < 16; o <<= 1) l += __shfl_xor(l, o, 64);
        float inv = 1.0f / l;
        short* pr = &sP[wi][(lq * 4 + r) * 72];
        pr[lr]      = f2b(e0 * inv);
        pr[16 + lr] = f2b(e1 * inv);
        pr[32 + lr] = f2b(e2 * inv);
        pr[48 + lr] = f2b(e3 * inv);
    }
    // wave-private sP slab: ds_write->ds_read ordered by lgkmcnt, no barrier

    // PV: A = own P rows (k=token), B rows = V^T[d][tok] gathered from global
    bf16x8 pa[2];
#pragma unroll
    for (int kk = 0; kk < 2; kk++)
        pa[kk] = *(const bf16x8*)&sP[wi][lr * 72 + kk * 32 + lq * 8];

#pragma unroll
    for (int half = 0; half < 2; half++) {
        const f32x4 fz = {0.f, 0.f, 0.f, 0.f};
        f32x4 o[4];
        bf16x8 pb[4][2];
#pragma unroll
        for (int j = 0; j < 4; j++)
#pragma unroll
            for (int kk = 0; kk < 2; kk++) {
                const int d = half * 64 + j * 16 + lr;
                const short* vcol = qkv + head * 192 + 64 + d;
                bf16x8 tvec;
#pragma unroll
                for (int e = 0; e < 8; e++) {
                    int tok = kk * 32 + lq * 8 + e;
                    tvec[e] = tok < NTOK ? vcol[(base + tok) * HQKV] : (short)0;
                }
                pb[j][kk] = tvec;
            }
#pragma unroll
        for (int j = 0; j < 4; j++) {
            o[j] = __builtin_amdgcn_mfma_f32_16x16x32_bf16(pa[0], pb[j][0], fz, 0, 0, 0);
            o[j] = __builtin_amdgcn_mfma_f32_16x16x32_bf16(pa[1], pb[j][1], o[j], 0, 0, 0);
        }
#pragma unroll
        for (int j = 0; j < 4; j++)
#pragma unroll
            for (int r = 0; r < 4; r++) {
                int row = wi * 16 + lq * 4 + r;
                if (row < NTOK)
                    attn_out[pack_off((int)(base + row),
                                      head * 128 + half * 64 + j * 16 + lr, 32)] =
                        f2f8(o[j][r]);
            }
    }
}

extern "C" void kernel_launch(void* const* d_in, const int* in_sizes, int n_in,
                              void* d_out, int out_size, void* d_ws, size_t ws_size,
                              hipStream_t stream) {
    const float* x      = (const float*)d_in[0];
    const float* qkv_w  = (const float*)d_in[1];
    const float* qkv_b  = (const float*)d_in[2];
    const float* proj_w = (const float*)d_in[3];
    const float* proj_b = (const float*)d_in[4];
    const float* fc1_w  = (const float*)d_in[5];
    const float* fc1_b  = (const float*)d_in[6];
    const float* fc2_w  = (const float*)d_in[7];
    const float* fc2_b  = (const float*)d_in[8];
    const float* n1g    = (const float*)d_in[9];
    const float* n1b    = (const float*)d_in[10];
    const float* n2g    = (const float*)d_in[11];
    const float* n2b    = (const float*)d_in[12];
    const float* ls1    = (const float*)d_in[13];
    const float* ls2    = (const float*)d_in[14];
    const float* biases = (const float*)d_in[15];
    const int*   bidx   = (const int*)d_in[16];
    float* outp = (float*)d_out;

    char* ws = (char*)d_ws;
    u8* Wq = (u8*)ws; ws += 688128;
    u8* Wp = (u8*)ws; ws += 458752;
    u8* W1 = (u8*)ws; ws += 802816;
    u8* W2 = (u8*)ws; ws += 802816;
    float* bfull = (float*)ws; ws += (size_t)NHEAD * NTOK * NTOK * 4;
    const size_t fixed = 2752512 + (size_t)NHEAD * NTOK * NTOK * 4;

    // per-row intermediates: hbuf 448 + qkvb 3072 + attb 1024 = 4544 B
    int IC = 1024;
    while (IC > 128) {
        size_t Rr = (size_t)IC * NTOK;
        if (fixed + Rr * 4544ull <= ws_size) break;
        IC >>= 1;
    }
    const size_t R = (size_t)IC * NTOK;
    u8*    hbuf = (u8*)ws;    ws += R * CDIM;       // LN out fp8 packed (reused LN2)
    short* qkvb = (short*)ws; ws += R * HQKV * 2;   // bf16 row-major (attn input)
    u8*    attb = (u8*)ws;    ws += R * DHID;       // attn out fp8 packed
    u8*    gbuf = (u8*)qkvb;  // FC1 out fp8 packed [R,1792] overlays qkvb

    convert_w<<<3136, 256, 0, stream>>>(qkv_w, proj_w, fc1_w, fc2_w,
                                        Wq, Wp, W1, W2, biases, bidx, bfull);

    for (int c0 = 0; c0 < 1024; c0 += IC) {
        const float* xc = x + (size_t)c0 * NTOK * CDIM;
        float* oc = outp + (size_t)c0 * NTOK * CDIM;
        const int Ri = IC * NTOK;
        const int gy = (Ri + 127) / 128;

        ln_kernel<<<Ri / 4, 256, 0, stream>>>(xc, hbuf, n1g, n1b);
        gemm_bt<0><<<dim3(HQKV / 128, gy), 256, 0, stream>>>(
            hbuf, Wq, qkv_b, nullptr, nullptr, nullptr, (void*)qkvb, Ri, HQKV, CDIM);
        attn_mfma<<<dim3(NHEAD, IC), 256, 0, stream>>>(qkvb, bfull, attb);
        // proj writes residual stream x + attn*ls1 straight into oc
        gemm_bt<2><<<dim3(4, gy), 256, 0, stream>>>(
            attb, Wp, proj_b, ls1, xc, oc, nullptr, Ri, CDIM, DHID);
        ln_kernel<<<Ri / 4, 256, 0, stream>>>(oc, hbuf, n2g, n2b);
        gemm_bt<1><<<dim3(FHID / 128, gy), 256, 0, stream>>>(
            hbuf, W1, fc1_b, nullptr, nullptr, nullptr, (void*)gbuf, Ri, FHID, CDIM);
        // fc2 in-place residual update: oc = oc + fc2(gbuf)*ls2
        gemm_bt<2><<<dim3(4, gy), 256, 0, stream>>>(
            gbuf, W2, fc2_b, ls2, oc, oc, nullptr, Ri, CDIM, FHID);
    }
}